// Round 6
// baseline (1707.642 us; speedup 1.0000x reference)
//
#include <hip/hip_runtime.h>
#include <stdint.h>

typedef unsigned short u16;
typedef __bf16 bf16x8 __attribute__((ext_vector_type(8)));
typedef float f32x4 __attribute__((ext_vector_type(4)));
typedef uint32_t u32x2 __attribute__((ext_vector_type(2)));
typedef uint32_t u32x4 __attribute__((ext_vector_type(4)));

#define NB 4
#define NC 512
#define NG 32
#define NSEQ 4096
#define NM (NB*NSEQ)

#define MFMA_(a,b,c) __builtin_amdgcn_mfma_f32_16x16x32_bf16(a,b,c,0,0,0)

__device__ __forceinline__ u16 f2bf(float f){
  uint32_t u = __builtin_bit_cast(uint32_t, f);
  u += 0x7FFFu + ((u >> 16) & 1u);
  return (u16)(u >> 16);
}
__device__ __forceinline__ float bfu(uint32_t lo16){
  return __builtin_bit_cast(float, lo16 << 16);
}
__device__ __forceinline__ uint32_t pk2(float a, float b){
  return (uint32_t)f2bf(a) | ((uint32_t)f2bf(b) << 16);
}

__device__ __forceinline__ void gll16(const void* g, void* l){
  __builtin_amdgcn_global_load_lds(
      (const __attribute__((address_space(1))) void*)g,
      (__attribute__((address_space(3))) void*)l, 16, 0, 0);
}

__global__ void k_zero(float* p, int n){
  int i = blockIdx.x*blockDim.x + threadIdx.x;
  if (i < n) p[i] = 0.f;
}

__global__ __launch_bounds__(256) void k_gn_stats(const float* __restrict__ x, float* __restrict__ stats){
  int blk = blockIdx.x;
  int ch = blk & 7, bg = blk >> 3;
  int g = bg & (NG-1), b = bg >> 5;
  int t = threadIdx.x;
  const float* base = x + (size_t)b*NSEQ*NC + g*16 + (t&3)*4;
  float s1 = 0.f, s2 = 0.f;
  for (int p = ch*512 + (t>>2); p < (ch+1)*512; p += 64){
    float4 v = *(const float4*)(base + (size_t)p*NC);
    s1 += v.x+v.y+v.z+v.w;
    s2 += v.x*v.x + v.y*v.y + v.z*v.z + v.w*v.w;
  }
  #pragma unroll
  for (int o = 32; o; o >>= 1){ s1 += __shfl_xor(s1, o); s2 += __shfl_xor(s2, o); }
  __shared__ float a1[4], a2[4];
  if ((t & 63) == 0){ a1[t>>6] = s1; a2[t>>6] = s2; }
  __syncthreads();
  if (t == 0){
    atomicAdd(&stats[bg*2+0], a1[0]+a1[1]+a1[2]+a1[3]);
    atomicAdd(&stats[bg*2+1], a2[0]+a2[1]+a2[2]+a2[3]);
  }
}

__global__ __launch_bounds__(256) void k_gn_apply(const float* __restrict__ x, const float* __restrict__ stats,
    const float* __restrict__ gsc, const float* __restrict__ gbi, u16* __restrict__ hn){
  const float inv_cnt = 1.f/((float)NSEQ*16.f);
  size_t total = (size_t)NM*NC/4;
  for (size_t i = (size_t)blockIdx.x*blockDim.x + threadIdx.x; i < total; i += (size_t)gridDim.x*blockDim.x){
    size_t flat = i*4;
    int c = (int)(flat & (NC-1));
    int b = (int)(flat >> 21);
    int g = c >> 4;
    float s1 = stats[(b*NG+g)*2], s2 = stats[(b*NG+g)*2+1];
    float mean = s1*inv_cnt;
    float rstd = rsqrtf(s2*inv_cnt - mean*mean + 1e-6f);
    float4 v = *(const float4*)(x + flat);
    float4 sc = *(const float4*)(gsc + c);
    float4 bi = *(const float4*)(gbi + c);
    ushort4 o;
    o.x = f2bf((v.x-mean)*rstd*sc.x + bi.x);
    o.y = f2bf((v.y-mean)*rstd*sc.y + bi.y);
    o.z = f2bf((v.z-mean)*rstd*sc.z + bi.z);
    o.w = f2bf((v.w-mean)*rstd*sc.w + bi.w);
    *(ushort4*)(hn + flat) = o;
  }
}

__global__ __launch_bounds__(256) void k_wtrans4(const float* __restrict__ wq, const float* __restrict__ wk,
    const float* __restrict__ wv, const float* __restrict__ wo,
    u16* __restrict__ wqkvT, u16* __restrict__ woT){
  int j = blockIdx.x*256 + threadIdx.x;
  int wsel = j >> 18, r = j & 262143;
  int n = r >> 9, k = r & 511;
  const float* src = wsel==0?wq : wsel==1?wk : wsel==2?wv : wo;
  u16 v = f2bf(src[k*512 + n]);
  if (wsel < 3) wqkvT[(size_t)wsel*262144 + r] = v;
  else          woT[r] = v;
}

__global__ __launch_bounds__(256) void k_sumred(const float* __restrict__ part, float* __restrict__ sums){
  int row = blockIdx.x*4 + (threadIdx.x >> 6);
  int l = threadIdx.x & 63;
  float s = part[(size_t)row*64 + l];
  #pragma unroll
  for (int o = 32; o; o >>= 1) s += __shfl_xor(s, o);
  if (l == 0) sums[row] = s;
}

__global__ __launch_bounds__(256) void k_pvred(const u16* __restrict__ op, const float* __restrict__ sums,
    u16* __restrict__ o){
  size_t i = ((size_t)blockIdx.x*256 + threadIdx.x)*8;
  int row = (int)(i >> 9);
  float inv = 1.f/sums[row];
  u32x4 a = __builtin_nontemporal_load((const u32x4*)(op + i));
  u32x4 b = __builtin_nontemporal_load((const u32x4*)(op + (size_t)NM*NC + i));
  uint32_t r[4];
  #pragma unroll
  for (int j=0;j<4;j++){
    float lo = (bfu(a[j] & 0xFFFFu) + bfu(b[j] & 0xFFFFu)) * inv;
    float hi = (__builtin_bit_cast(float, a[j] & 0xFFFF0000u) +
                __builtin_bit_cast(float, b[j] & 0xFFFF0000u)) * inv;
    r[j] = (uint32_t)f2bf(lo) | ((uint32_t)f2bf(hi) << 16);
  }
  *(uint4*)(o + i) = make_uint4(r[0], r[1], r[2], r[3]);
}

// ------- 256x256 GEMM, BK=32, 2-phase/K-tile, 64 KB LDS -> 2 blocks/CU -------
// LDS swizzle: physical byte(rl,kq) = (rl>>1)*128 + ((((rl&1)<<2)|kq) ^ ((rl>>2)&7))*16
// -> bank-balanced for stride-1 A-frag reads AND stride-4 remapped B-frag reads;
// gll16 source carries the inverse permutation (linear LDS dest).
#define PH_A  { __builtin_amdgcn_sched_barrier(0); __builtin_amdgcn_s_barrier(); \
  asm volatile("s_waitcnt lgkmcnt(0)" ::: "memory"); __builtin_amdgcn_sched_barrier(0); \
  __builtin_amdgcn_s_setprio(1); }
#define PH_B  { __builtin_amdgcn_s_setprio(0); __builtin_amdgcn_sched_barrier(0); \
  __builtin_amdgcn_s_barrier(); }
#define PH_BV0 { __builtin_amdgcn_s_setprio(0); __builtin_amdgcn_sched_barrier(0); \
  asm volatile("s_waitcnt vmcnt(0)" ::: "memory"); __builtin_amdgcn_s_barrier(); }

template<int MODE>
__global__ __launch_bounds__(512, 4) void k_gemm2(
    const u16* __restrict__ A, const u16* __restrict__ B,
    size_t aBatch, size_t bBatch, int lda_, int ldb_, int Klen, float alpha,
    void* __restrict__ out0, void* __restrict__ out1, void* __restrict__ out2,
    const float* __restrict__ bias0, const float* __restrict__ bias1, const float* __restrict__ bias2,
    const float* __restrict__ aux1)
{
  __shared__ u16 LDS[32768];   // 64 KiB: 2 buf x (A 16K + B 16K)
  const size_t lda = lda_, ldb = ldb_;
  const int t = threadIdx.x;
  const int l = t & 63, w = t >> 6;
  const int wr = w >> 2, wc = w & 3;
  const int frow = l & 15, kq = l >> 4;
  // XCD-aware bijective remap (all grids have nwg%8==0)
  const int nx = gridDim.x, ny = gridDim.y;
  int f = ((int)blockIdx.z*ny + (int)blockIdx.y)*nx + (int)blockIdx.x;
  const int nwg = nx*ny*(int)gridDim.z;
  f = (f & 7)*(nwg >> 3) + (f >> 3);
  const int bx = f % nx; const int t2 = f / nx;
  const int by = t2 % ny; const int bz = t2 / ny;
  int bb = 0, kOff = 0;
  if constexpr (MODE == 1) bb = bz;
  if constexpr (MODE == 4){ bb = bz & 3; kOff = (bz >> 2)*(NSEQ/2); }
  const int brow = by*256, bcol = bx*256;

  f32x4 acc[8][4] = {};
  // staging thread map (inverse of read swizzle): thread t -> row rlloc, k-slot u&3
  const int u = (t & 7) ^ ((t >> 4) & 7);
  const int rlloc = ((t >> 3) << 1) | (u >> 2);
  const u16* Asrc = A + (size_t)bb*aBatch + (size_t)(brow + rlloc)*lda + (u & 3)*8 + kOff;
  const u16* Bsrc = B + (size_t)bb*bBatch + (size_t)(bcol + rlloc)*ldb + (u & 3)*8 + kOff;
  char* Lb = (char*)LDS;
  char* dstA = Lb + t*16;
  char* dstB = Lb + 16384 + t*16;

  auto stage = [&](int buf, int kt){
    const size_t ko = (size_t)kt*32;
    gll16(Asrc + ko,                     dstA + buf*32768);
    gll16(Asrc + (size_t)128*lda + ko,   dstA + buf*32768 + 8192);
    gll16(Bsrc + ko,                     dstB + buf*32768);
    gll16(Bsrc + (size_t)128*ldb + ko,   dstB + buf*32768 + 8192);
  };
  auto ldA = [&](int buf, int qr, bf16x8* dst){
    const char* base = Lb + buf*32768;
    #pragma unroll
    for (int mf=0; mf<4; mf++){
      int rl = wr*128 + qr*64 + mf*16 + frow;
      int byte = ((rl>>1)<<7) + (((((rl&1)<<2)|kq) ^ ((rl>>2)&7))<<4);
      dst[mf] = *(const bf16x8*)(base + byte);
    }
  };
  auto ldB = [&](int buf, bf16x8* dst){
    const char* base = Lb + buf*32768 + 16384;
    #pragma unroll
    for (int c=0; c<4; c++){
      int rl = wc*64 + 4*frow + c;     // col remap: lane's 4 n-values adjacent
      int byte = ((rl>>1)<<7) + (((((rl&1)<<2)|kq) ^ ((rl>>2)&7))<<4);
      dst[c] = *(const bf16x8*)(base + byte);
    }
  };
  auto quadrow = [&](int qr, const bf16x8* a4, const bf16x8* b4){
    #pragma unroll
    for (int mf=0; mf<4; mf++)
      #pragma unroll
      for (int c=0; c<4; c++)
        acc[qr*4+mf][c] = MFMA_(a4[mf], b4[c], acc[qr*4+mf][c]);
  };

  const int NT = Klen >> 5;
  stage(0, 0);
  asm volatile("s_waitcnt vmcnt(0)" ::: "memory");
  __builtin_amdgcn_s_barrier();

  for (int s = 0; s < NT; s++){
    const int cur = s & 1;
    const int nk = (s+1 < NT) ? (s+1) : (NT-1);
    bf16x8 a4[4], b4[4];
    // P1: reads of current buf + stage next tile into the OTHER buf (WAR-safe)
    ldA(cur, 0, a4); ldB(cur, b4);
    stage(cur^1, nk);
    PH_A; quadrow(0, a4, b4); PH_B;
    // P2
    ldA(cur, 1, a4);
    PH_A; quadrow(1, a4, b4); PH_BV0;
  }

  // ---------------- epilogue (packed coalesced stores) ----------------
  const int col4 = wc*64 + 4*frow;
  if constexpr (MODE==0){
    const int seg = bcol >> 9;
    const int colr = (bcol & 511) + col4;
    if (seg < 2){
      u16* dq = (u16*)(seg==0 ? out0 : out1);
      const float* bp = seg==0 ? bias0 : bias1;
      const float4 bi = *(const float4*)(bp + colr);
      #pragma unroll
      for (int m=0;m<8;m++){
        #pragma unroll
        for (int r=0;r<4;r++){
          const int rr = brow + wr*128 + m*16 + kq*4 + r;
          u32x2 wv;
          wv[0] = pk2(acc[m][0][r]+bi.x, acc[m][1][r]+bi.y);
          wv[1] = pk2(acc[m][2][r]+bi.z, acc[m][3][r]+bi.w);
          *(u32x2*)&dq[(size_t)rr*NC + colr] = wv;
        }
      }
    } else {
      const float4 bi = *(const float4*)(bias2 + colr);
      const float bvs[4] = {bi.x, bi.y, bi.z, bi.w};
      #pragma unroll
      for (int m=0;m<8;m++){
        const int rr0 = brow + wr*128 + m*16 + kq*4;
        const int b = rr0 >> 12, sq = rr0 & 4095;
        #pragma unroll
        for (int n=0;n<4;n++){
          u32x2 wv;
          wv[0] = pk2(acc[m][n][0]+bvs[n], acc[m][n][1]+bvs[n]);
          wv[1] = pk2(acc[m][n][2]+bvs[n], acc[m][n][3]+bvs[n]);
          *(u32x2*)&((u16*)out2)[((size_t)(b*NC + colr + n) << 12) + sq] = wv;
        }
      }
    }
  } else if constexpr (MODE==1){
    u16* Pp = (u16*)out0 + (size_t)bb*NSEQ*NSEQ;
    #pragma unroll
    for (int m=0;m<8;m++){
      #pragma unroll
      for (int r=0;r<4;r++){
        const int rr = brow + wr*128 + m*16 + kq*4 + r;
        float e0 = __expf(alpha*acc[m][0][r]);
        float e1 = __expf(alpha*acc[m][1][r]);
        float e2 = __expf(alpha*acc[m][2][r]);
        float e3 = __expf(alpha*acc[m][3][r]);
        u32x2 wv; wv[0] = pk2(e0, e1); wv[1] = pk2(e2, e3);
        __builtin_nontemporal_store(wv, (u32x2*)&Pp[(size_t)rr*NSEQ + bcol + col4]);
        float rs = bfu(wv[0] & 0xFFFFu) + bfu(wv[0] >> 16) + bfu(wv[1] & 0xFFFFu) + bfu(wv[1] >> 16);
        rs += __shfl_xor(rs, 1); rs += __shfl_xor(rs, 2);
        rs += __shfl_xor(rs, 4); rs += __shfl_xor(rs, 8);
        if (frow == 0)
          ((float*)out1)[((size_t)bb*NSEQ + rr)*64 + bx*4 + wc] = rs;
      }
    }
  } else if constexpr (MODE==4){
    const int sp = bz >> 2;
    u16* op = (u16*)out0 + (size_t)sp*NM*NC + (size_t)bb*NSEQ*NC;
    #pragma unroll
    for (int m=0;m<8;m++){
      #pragma unroll
      for (int r=0;r<4;r++){
        const int rr = brow + wr*128 + m*16 + kq*4 + r;
        u32x2 wv;
        wv[0] = pk2(acc[m][0][r], acc[m][1][r]);
        wv[1] = pk2(acc[m][2][r], acc[m][3][r]);
        __builtin_nontemporal_store(wv, (u32x2*)&op[(size_t)rr*NC + bcol + col4]);
      }
    }
  } else {
    const int c = bcol + col4;
    const float4 bi = *(const float4*)(bias0 + c);
    #pragma unroll
    for (int m=0;m<8;m++){
      #pragma unroll
      for (int r=0;r<4;r++){
        const int rr = brow + wr*128 + m*16 + kq*4 + r;
        const float4 res = *(const float4*)(aux1 + (size_t)rr*NC + c);
        float4 ov;
        ov.x = acc[m][0][r] + bi.x + res.x;
        ov.y = acc[m][1][r] + bi.y + res.y;
        ov.z = acc[m][2][r] + bi.z + res.z;
        ov.w = acc[m][3][r] + bi.w + res.w;
        *(float4*)&((float*)out0)[(size_t)rr*NC + c] = ov;
      }
    }
  }
}

extern "C" void kernel_launch(void* const* d_in, const int* in_sizes, int n_in,
                              void* d_out, int out_size, void* d_ws, size_t ws_size,
                              hipStream_t stream){
  const float* x   = (const float*)d_in[0];
  const float* gsc = (const float*)d_in[1];
  const float* gbi = (const float*)d_in[2];
  const float* wq  = (const float*)d_in[3];
  const float* bq  = (const float*)d_in[4];
  const float* wk  = (const float*)d_in[5];
  const float* bk  = (const float*)d_in[6];
  const float* wv  = (const float*)d_in[7];
  const float* bv  = (const float*)d_in[8];
  const float* wo  = (const float*)d_in[9];
  const float* bo  = (const float*)d_in[10];
  float* out = (float*)d_out;

  char* wsp = (char*)d_ws;
  size_t off = 0;
  auto alloc = [&](size_t bytes)->void*{ void* p = wsp + off; off += (bytes + 255) & ~(size_t)255; return p; };
  float* stats   = (float*)alloc((size_t)NB*NG*2*sizeof(float));
  float* sums    = (float*)alloc((size_t)NM*sizeof(float));
  float* partsum = (float*)alloc((size_t)NM*64*sizeof(float));
  u16* hn    = (u16*)alloc((size_t)NM*NC*2);
  u16* wqkvT = (u16*)alloc((size_t)3*NC*NC*2);
  u16* woT   = (u16*)alloc((size_t)NC*NC*2);
  u16* q     = (u16*)alloc((size_t)NM*NC*2);
  u16* kk    = (u16*)alloc((size_t)NM*NC*2);
  u16* vT    = (u16*)alloc((size_t)NM*NC*2);
  u16* o     = (u16*)alloc((size_t)NM*NC*2);
  u16* P     = (u16*)alloc((size_t)NB*NSEQ*NSEQ*2);
  u16* opart = q;  // PV split-K partials [2][NM][NC] alias dead q+kk (32 MiB)

  k_zero<<<1,256,0,stream>>>(stats, NB*NG*2);
  k_gn_stats<<<NB*NG*8,256,0,stream>>>(x, stats);
  k_gn_apply<<<2048,256,0,stream>>>(x, stats, gsc, gbi, hn);
  k_wtrans4<<<4096,256,0,stream>>>(wq, wk, wv, wo, wqkvT, woT);

  // QKV projection: M=16384, N=1536, K=512
  k_gemm2<0><<<dim3(6,64,1),512,0,stream>>>(hn, wqkvT, 0, 0, NC, NC, NC, 1.f,
      q, kk, vT, bq, bk, bv, nullptr);

  const float scale = 0.044194173824159216f;  // 512^-0.5
  // QK^T all batches + exp + row partials: M=N=4096, K=512, z=4
  k_gemm2<1><<<dim3(16,16,NB),512,0,stream>>>(q, kk,
      (size_t)NSEQ*NC, (size_t)NSEQ*NC, NC, NC, NC, scale,
      P, partsum, nullptr, nullptr, nullptr, nullptr, nullptr);
  k_sumred<<<NM/4,256,0,stream>>>(partsum, sums);
  // PV split-K=2: M=4096, N=512, Klen=2048, z=(split,b) -> 256 blocks
  k_gemm2<4><<<dim3(2,16,8),512,0,stream>>>(P, vT,
      (size_t)NSEQ*NSEQ, (size_t)NC*NSEQ, NSEQ, NSEQ, NSEQ/2, 1.f,
      opart, nullptr, nullptr, nullptr, nullptr, nullptr, nullptr);
  k_pvred<<<NM*NC/8/256,256,0,stream>>>(opart, sums, o);
  // output projection + bias + residual: M=16384, N=512, K=512
  k_gemm2<3><<<dim3(2,64,1),512,0,stream>>>(o, woT, 0, 0, NC, NC, NC, 1.f,
      out, nullptr, nullptr, bo, nullptr, nullptr, x);
}

// Round 7
// 309.116 us; speedup vs baseline: 5.5243x; 5.5243x over previous
//
#include <hip/hip_runtime.h>
#include <stdint.h>

typedef unsigned short u16;
typedef __bf16 bf16x8 __attribute__((ext_vector_type(8)));
typedef float f32x4 __attribute__((ext_vector_type(4)));
typedef uint32_t u32x2 __attribute__((ext_vector_type(2)));
typedef uint32_t u32x4 __attribute__((ext_vector_type(4)));

#define NB 4
#define NC 512
#define NG 32
#define NSEQ 4096
#define NM (NB*NSEQ)

#define MFMA_(a,b,c) __builtin_amdgcn_mfma_f32_16x16x32_bf16(a,b,c,0,0,0)

__device__ __forceinline__ u16 f2bf(float f){
  uint32_t u = __builtin_bit_cast(uint32_t, f);
  u += 0x7FFFu + ((u >> 16) & 1u);
  return (u16)(u >> 16);
}
__device__ __forceinline__ float bfu(uint32_t lo16){
  return __builtin_bit_cast(float, lo16 << 16);
}
__device__ __forceinline__ uint32_t pk2(float a, float b){
  return (uint32_t)f2bf(a) | ((uint32_t)f2bf(b) << 16);
}

__device__ __forceinline__ void gll16(const void* g, void* l){
  __builtin_amdgcn_global_load_lds(
      (const __attribute__((address_space(1))) void*)g,
      (__attribute__((address_space(3))) void*)l, 16, 0, 0);
}

__global__ void k_zero(float* p, int n){
  int i = blockIdx.x*blockDim.x + threadIdx.x;
  if (i < n) p[i] = 0.f;
}

__global__ __launch_bounds__(256) void k_gn_stats(const float* __restrict__ x, float* __restrict__ stats){
  int blk = blockIdx.x;
  int ch = blk & 7, bg = blk >> 3;
  int g = bg & (NG-1), b = bg >> 5;
  int t = threadIdx.x;
  const float* base = x + (size_t)b*NSEQ*NC + g*16 + (t&3)*4;
  float s1 = 0.f, s2 = 0.f;
  for (int p = ch*512 + (t>>2); p < (ch+1)*512; p += 64){
    float4 v = *(const float4*)(base + (size_t)p*NC);
    s1 += v.x+v.y+v.z+v.w;
    s2 += v.x*v.x + v.y*v.y + v.z*v.z + v.w*v.w;
  }
  #pragma unroll
  for (int o = 32; o; o >>= 1){ s1 += __shfl_xor(s1, o); s2 += __shfl_xor(s2, o); }
  __shared__ float a1[4], a2[4];
  if ((t & 63) == 0){ a1[t>>6] = s1; a2[t>>6] = s2; }
  __syncthreads();
  if (t == 0){
    atomicAdd(&stats[bg*2+0], a1[0]+a1[1]+a1[2]+a1[3]);
    atomicAdd(&stats[bg*2+1], a2[0]+a2[1]+a2[2]+a2[3]);
  }
}

__global__ __launch_bounds__(256) void k_gn_apply(const float* __restrict__ x, const float* __restrict__ stats,
    const float* __restrict__ gsc, const float* __restrict__ gbi, u16* __restrict__ hn){
  const float inv_cnt = 1.f/((float)NSEQ*16.f);
  size_t total = (size_t)NM*NC/4;
  for (size_t i = (size_t)blockIdx.x*blockDim.x + threadIdx.x; i < total; i += (size_t)gridDim.x*blockDim.x){
    size_t flat = i*4;
    int c = (int)(flat & (NC-1));
    int b = (int)(flat >> 21);
    int g = c >> 4;
    float s1 = stats[(b*NG+g)*2], s2 = stats[(b*NG+g)*2+1];
    float mean = s1*inv_cnt;
    float rstd = rsqrtf(s2*inv_cnt - mean*mean + 1e-6f);
    float4 v = *(const float4*)(x + flat);
    float4 sc = *(const float4*)(gsc + c);
    float4 bi = *(const float4*)(gbi + c);
    ushort4 o;
    o.x = f2bf((v.x-mean)*rstd*sc.x + bi.x);
    o.y = f2bf((v.y-mean)*rstd*sc.y + bi.y);
    o.z = f2bf((v.z-mean)*rstd*sc.z + bi.z);
    o.w = f2bf((v.w-mean)*rstd*sc.w + bi.w);
    *(ushort4*)(hn + flat) = o;
  }
}

__global__ __launch_bounds__(256) void k_wtrans4(const float* __restrict__ wq, const float* __restrict__ wk,
    const float* __restrict__ wv, const float* __restrict__ wo,
    u16* __restrict__ wqkvT, u16* __restrict__ woT){
  int j = blockIdx.x*256 + threadIdx.x;
  int wsel = j >> 18, r = j & 262143;
  int n = r >> 9, k = r & 511;
  const float* src = wsel==0?wq : wsel==1?wk : wsel==2?wv : wo;
  u16 v = f2bf(src[k*512 + n]);
  if (wsel < 3) wqkvT[(size_t)wsel*262144 + r] = v;
  else          woT[r] = v;
}

__global__ __launch_bounds__(256) void k_sumred(const float* __restrict__ part, float* __restrict__ sums){
  int row = blockIdx.x*4 + (threadIdx.x >> 6);
  int l = threadIdx.x & 63;
  float s = part[(size_t)row*64 + l];
  #pragma unroll
  for (int o = 32; o; o >>= 1) s += __shfl_xor(s, o);
  if (l == 0) sums[row] = s;
}

__global__ __launch_bounds__(256) void k_pvred(const u16* __restrict__ op, const float* __restrict__ sums,
    u16* __restrict__ o){
  size_t i = ((size_t)blockIdx.x*256 + threadIdx.x)*8;
  int row = (int)(i >> 9);
  float inv = 1.f/sums[row];
  u32x4 a = __builtin_nontemporal_load((const u32x4*)(op + i));
  u32x4 b = __builtin_nontemporal_load((const u32x4*)(op + (size_t)NM*NC + i));
  uint32_t r[4];
  #pragma unroll
  for (int j=0;j<4;j++){
    float lo = (bfu(a[j] & 0xFFFFu) + bfu(b[j] & 0xFFFFu)) * inv;
    float hi = (__builtin_bit_cast(float, a[j] & 0xFFFF0000u) +
                __builtin_bit_cast(float, b[j] & 0xFFFF0000u)) * inv;
    r[j] = (uint32_t)f2bf(lo) | ((uint32_t)f2bf(hi) << 16);
  }
  *(uint4*)(o + i) = make_uint4(r[0], r[1], r[2], r[3]);
}

// ---- 128x128 GEMM, 4 waves, BK=32, ring-3 LDS bufs, counted vmcnt(4) ----
// 48 KB LDS + ~120 VGPR -> 3 blocks/CU (12 waves): cross-block overlap hides
// barrier/prologue/epilogue stalls (m97 mechanism) while vmcnt(4) keeps the
// next tile's loads in flight across barriers (never drain to 0 mid-loop).
// MODE 0: QKV (q,k row-major; v transposed per-batch) + bias
// MODE 1: QK^T: P = exp(alpha*acc) bf16 + per-(row,64col) f32 partial sums
// MODE 3: f32 out + bias + residual
// MODE 4: PV split-K: z=(split,b); bf16 partial out
template<int MODE>
__global__ __launch_bounds__(256, 3) void k_gemm3(
    const u16* __restrict__ A, const u16* __restrict__ B,
    size_t aBatch, size_t bBatch, int lda_, int ldb_, int Klen, float alpha,
    void* __restrict__ out0, void* __restrict__ out1, void* __restrict__ out2,
    const float* __restrict__ bias0, const float* __restrict__ bias1, const float* __restrict__ bias2,
    const float* __restrict__ aux1)
{
  __shared__ u16 LDS[24576];   // 48 KiB: 3 bufs x (A 8K + B 8K)
  const size_t lda = lda_, ldb = ldb_;
  const int t = threadIdx.x;
  const int l = t & 63, w = t >> 6;
  const int wr = w >> 1, wc = w & 1;
  const int frow = l & 15, kq = l >> 4;
  // XCD-aware bijective remap (all grids have nwg%8==0)
  const int nx = gridDim.x, ny = gridDim.y;
  int f = ((int)blockIdx.z*ny + (int)blockIdx.y)*nx + (int)blockIdx.x;
  const int nwg = nx*ny*(int)gridDim.z;
  f = (f & 7)*(nwg >> 3) + (f >> 3);
  const int bx = f % nx; const int t2 = f / nx;
  const int by = t2 % ny; const int bz = t2 / ny;
  int bb = 0, kOff = 0;
  if constexpr (MODE == 1) bb = bz;
  if constexpr (MODE == 4){ bb = bz & 3; kOff = (bz >> 2)*(NSEQ/2); }
  const int brow = by*128, bcol = bx*128;

  f32x4 acc[4][4] = {};
  // staging: thread t covers row t>>2, 16B-slot t&3; +64-row for 2nd call.
  const u16* Asrc = A + (size_t)bb*aBatch + (size_t)(brow + (t>>2))*lda + (t&3)*8 + kOff;
  const u16* Bsrc = B + (size_t)bb*bBatch + (size_t)(bcol + (t>>2))*ldb + (t&3)*8 + kOff;
  char* Lb = (char*)LDS;
  char* dA = Lb + t*16;
  char* dB = Lb + 8192 + t*16;

  auto stage = [&](int buf, int kt){
    const size_t ko = (size_t)kt*32;
    gll16(Asrc + ko,                    dA + buf*16384);
    gll16(Asrc + (size_t)64*lda + ko,   dA + buf*16384 + 4096);
    gll16(Bsrc + ko,                    dB + buf*16384);
    gll16(Bsrc + (size_t)64*ldb + ko,   dB + buf*16384 + 4096);
  };
  auto ldA = [&](int buf, bf16x8* dst){
    const char* base = Lb + buf*16384;
    #pragma unroll
    for (int m=0; m<4; m++){
      int rl = wr*64 + m*16 + frow;
      dst[m] = *(const bf16x8*)(base + rl*64 + kq*16);
    }
  };
  auto ldB = [&](int buf, bf16x8* dst){
    const char* base = Lb + buf*16384 + 8192;
    #pragma unroll
    for (int c=0; c<4; c++){
      int rl = wc*64 + 4*frow + c;   // col remap: lane's 4 n-values adjacent
      dst[c] = *(const bf16x8*)(base + rl*64 + kq*16);
    }
  };

  const int NT = Klen >> 5;
  // prologue: tiles 0,1 into bufs 0,1
  stage(0, 0); stage(1, 1);
  asm volatile("s_waitcnt vmcnt(4)" ::: "memory");   // tile 0 landed; tile 1 in flight
  __builtin_amdgcn_s_barrier();

  int cur = 0;
  for (int s = 0; s < NT; s++){
    bf16x8 a4[4], b4[4];
    ldA(cur, a4); ldB(cur, b4);
    int nxt = cur + 1; if (nxt == 3) nxt = 0;
    int n2 = nxt + 1; if (n2 == 3) n2 = 0;
    if (s + 2 < NT) stage(n2, s + 2);     // tile s+2 -> buf (s+2)%3
    asm volatile("s_waitcnt lgkmcnt(0)" ::: "memory");
    __builtin_amdgcn_sched_barrier(0);
    __builtin_amdgcn_s_setprio(1);
    #pragma unroll
    for (int m=0; m<4; m++)
      #pragma unroll
      for (int c=0; c<4; c++)
        acc[m][c] = MFMA_(a4[m], b4[c], acc[m][c]);
    __builtin_amdgcn_s_setprio(0);
    __builtin_amdgcn_sched_barrier(0);
    if (s + 1 < NT){
      if (s + 2 < NT) asm volatile("s_waitcnt vmcnt(4)" ::: "memory");  // tile s+1 landed
      else            asm volatile("s_waitcnt vmcnt(0)" ::: "memory");
      __builtin_amdgcn_s_barrier();
    }
    cur = nxt;
  }

  // ---------------- epilogue (packed coalesced stores) ----------------
  const int col4 = wc*64 + 4*frow;
  if constexpr (MODE==0){
    const int seg = bcol >> 9;
    const int colr = (bcol & 511) + col4;
    if (seg < 2){
      u16* dq = (u16*)(seg==0 ? out0 : out1);
      const float* bp = seg==0 ? bias0 : bias1;
      const float4 bi = *(const float4*)(bp + colr);
      #pragma unroll
      for (int m=0;m<4;m++){
        #pragma unroll
        for (int r=0;r<4;r++){
          const int rr = brow + wr*64 + m*16 + kq*4 + r;
          u32x2 wv;
          wv[0] = pk2(acc[m][0][r]+bi.x, acc[m][1][r]+bi.y);
          wv[1] = pk2(acc[m][2][r]+bi.z, acc[m][3][r]+bi.w);
          *(u32x2*)&dq[(size_t)rr*NC + colr] = wv;
        }
      }
    } else {
      const float4 bi = *(const float4*)(bias2 + colr);
      const float bvs[4] = {bi.x, bi.y, bi.z, bi.w};
      #pragma unroll
      for (int m=0;m<4;m++){
        const int rr0 = brow + wr*64 + m*16 + kq*4;
        const int b = rr0 >> 12, sq = rr0 & 4095;
        #pragma unroll
        for (int n=0;n<4;n++){
          u32x2 wv;
          wv[0] = pk2(acc[m][n][0]+bvs[n], acc[m][n][1]+bvs[n]);
          wv[1] = pk2(acc[m][n][2]+bvs[n], acc[m][n][3]+bvs[n]);
          *(u32x2*)&((u16*)out2)[((size_t)(b*NC + colr + n) << 12) + sq] = wv;
        }
      }
    }
  } else if constexpr (MODE==1){
    u16* Pp = (u16*)out0 + (size_t)bb*NSEQ*NSEQ;
    #pragma unroll
    for (int m=0;m<4;m++){
      #pragma unroll
      for (int r=0;r<4;r++){
        const int rr = brow + wr*64 + m*16 + kq*4 + r;
        float e0 = __expf(alpha*acc[m][0][r]);
        float e1 = __expf(alpha*acc[m][1][r]);
        float e2 = __expf(alpha*acc[m][2][r]);
        float e3 = __expf(alpha*acc[m][3][r]);
        u32x2 wv; wv[0] = pk2(e0, e1); wv[1] = pk2(e2, e3);
        __builtin_nontemporal_store(wv, (u32x2*)&Pp[(size_t)rr*NSEQ + bcol + col4]);
        float rs = bfu(wv[0] & 0xFFFFu) + bfu(wv[0] >> 16) + bfu(wv[1] & 0xFFFFu) + bfu(wv[1] >> 16);
        rs += __shfl_xor(rs, 1); rs += __shfl_xor(rs, 2);
        rs += __shfl_xor(rs, 4); rs += __shfl_xor(rs, 8);
        if (frow == 0)
          ((float*)out1)[((size_t)bb*NSEQ + rr)*64 + bx*2 + wc] = rs;
      }
    }
  } else if constexpr (MODE==4){
    const int sp = bz >> 2;
    u16* op = (u16*)out0 + (size_t)sp*NM*NC + (size_t)bb*NSEQ*NC;
    #pragma unroll
    for (int m=0;m<4;m++){
      #pragma unroll
      for (int r=0;r<4;r++){
        const int rr = brow + wr*64 + m*16 + kq*4 + r;
        u32x2 wv;
        wv[0] = pk2(acc[m][0][r], acc[m][1][r]);
        wv[1] = pk2(acc[m][2][r], acc[m][3][r]);
        __builtin_nontemporal_store(wv, (u32x2*)&op[(size_t)rr*NC + bcol + col4]);
      }
    }
  } else {
    const int c = bcol + col4;
    const float4 bi = *(const float4*)(bias0 + c);
    #pragma unroll
    for (int m=0;m<4;m++){
      #pragma unroll
      for (int r=0;r<4;r++){
        const int rr = brow + wr*64 + m*16 + kq*4 + r;
        const float4 res = *(const float4*)(aux1 + (size_t)rr*NC + c);
        float4 ov;
        ov.x = acc[m][0][r] + bi.x + res.x;
        ov.y = acc[m][1][r] + bi.y + res.y;
        ov.z = acc[m][2][r] + bi.z + res.z;
        ov.w = acc[m][3][r] + bi.w + res.w;
        *(float4*)&((float*)out0)[(size_t)rr*NC + c] = ov;
      }
    }
  }
}

extern "C" void kernel_launch(void* const* d_in, const int* in_sizes, int n_in,
                              void* d_out, int out_size, void* d_ws, size_t ws_size,
                              hipStream_t stream){
  const float* x   = (const float*)d_in[0];
  const float* gsc = (const float*)d_in[1];
  const float* gbi = (const float*)d_in[2];
  const float* wq  = (const float*)d_in[3];
  const float* bq  = (const float*)d_in[4];
  const float* wk  = (const float*)d_in[5];
  const float* bk  = (const float*)d_in[6];
  const float* wv  = (const float*)d_in[7];
  const float* bv  = (const float*)d_in[8];
  const float* wo  = (const float*)d_in[9];
  const float* bo  = (const float*)d_in[10];
  float* out = (float*)d_out;

  char* wsp = (char*)d_ws;
  size_t off = 0;
  auto alloc = [&](size_t bytes)->void*{ void* p = wsp + off; off += (bytes + 255) & ~(size_t)255; return p; };
  float* stats   = (float*)alloc((size_t)NB*NG*2*sizeof(float));
  float* sums    = (float*)alloc((size_t)NM*sizeof(float));
  float* partsum = (float*)alloc((size_t)NM*64*sizeof(float));
  u16* hn    = (u16*)alloc((size_t)NM*NC*2);
  u16* wqkvT = (u16*)alloc((size_t)3*NC*NC*2);
  u16* woT   = (u16*)alloc((size_t)NC*NC*2);
  u16* q     = (u16*)alloc((size_t)NM*NC*2);
  u16* kk    = (u16*)alloc((size_t)NM*NC*2);
  u16* vT    = (u16*)alloc((size_t)NM*NC*2);
  u16* o     = (u16*)alloc((size_t)NM*NC*2);
  u16* P     = (u16*)alloc((size_t)NB*NSEQ*NSEQ*2);
  u16* opart = q;  // PV split-K partials [2][NM][NC] alias dead q+kk (32 MiB)

  k_zero<<<1,256,0,stream>>>(stats, NB*NG*2);
  k_gn_stats<<<NB*NG*8,256,0,stream>>>(x, stats);
  k_gn_apply<<<2048,256,0,stream>>>(x, stats, gsc, gbi, hn);
  k_wtrans4<<<4096,256,0,stream>>>(wq, wk, wv, wo, wqkvT, woT);

  // QKV projection: M=16384, N=1536, K=512
  k_gemm3<0><<<dim3(12,128,1),256,0,stream>>>(hn, wqkvT, 0, 0, NC, NC, NC, 1.f,
      q, kk, vT, bq, bk, bv, nullptr);

  const float scale = 0.044194173824159216f;  // 512^-0.5
  // QK^T all batches + exp + row partials: M=N=4096, K=512, z=4
  k_gemm3<1><<<dim3(32,32,NB),256,0,stream>>>(q, kk,
      (size_t)NSEQ*NC, (size_t)NSEQ*NC, NC, NC, NC, scale,
      P, partsum, nullptr, nullptr, nullptr, nullptr, nullptr);
  k_sumred<<<NM/4,256,0,stream>>>(partsum, sums);
  // PV split-K=2: M=4096, N=512, Klen=2048, z=(split,b) -> 1024 blocks
  k_gemm3<4><<<dim3(4,32,8),256,0,stream>>>(P, vT,
      (size_t)NSEQ*NSEQ, (size_t)NC*NSEQ, NSEQ, NSEQ, NSEQ/2, 1.f,
      opart, nullptr, nullptr, nullptr, nullptr, nullptr, nullptr);
  k_pvred<<<NM*NC/8/256,256,0,stream>>>(opart, sums, o);
  // output projection + bias + residual: M=16384, N=512, K=512
  k_gemm3<3><<<dim3(4,128,1),256,0,stream>>>(o, woT, 0, 0, NC, NC, NC, 1.f,
      out, nullptr, nullptr, bo, nullptr, nullptr, x);
}

// Round 8
// 262.102 us; speedup vs baseline: 6.5152x; 1.1794x over previous
//
#include <hip/hip_runtime.h>
#include <stdint.h>

typedef unsigned short u16;
typedef __bf16 bf16x8 __attribute__((ext_vector_type(8)));
typedef float f32x4 __attribute__((ext_vector_type(4)));
typedef uint32_t u32x2 __attribute__((ext_vector_type(2)));
typedef uint32_t u32x4 __attribute__((ext_vector_type(4)));

#define NB 4
#define NC 512
#define NG 32
#define NSEQ 4096
#define NM (NB*NSEQ)

#define MFMA_(a,b,c) __builtin_amdgcn_mfma_f32_16x16x32_bf16(a,b,c,0,0,0)
// 256^2 8-phase kernel's swizzle (round-5, unchanged)
#define SWZ(rl) (((((rl) ^ ((rl)>>2)) & 7)) << 4)

__device__ __forceinline__ u16 f2bf(float f){
  uint32_t u = __builtin_bit_cast(uint32_t, f);
  u += 0x7FFFu + ((u >> 16) & 1u);
  return (u16)(u >> 16);
}
__device__ __forceinline__ float bfu(uint32_t lo16){
  return __builtin_bit_cast(float, lo16 << 16);
}
__device__ __forceinline__ uint32_t pk2(float a, float b){
  return (uint32_t)f2bf(a) | ((uint32_t)f2bf(b) << 16);
}

__device__ __forceinline__ void gll16(const void* g, void* l){
  __builtin_amdgcn_global_load_lds(
      (const __attribute__((address_space(1))) void*)g,
      (__attribute__((address_space(3))) void*)l, 16, 0, 0);
}

__global__ void k_zero(float* p, int n){
  int i = blockIdx.x*blockDim.x + threadIdx.x;
  if (i < n) p[i] = 0.f;
}

__global__ __launch_bounds__(256) void k_gn_stats(const float* __restrict__ x, float* __restrict__ stats){
  int blk = blockIdx.x;
  int ch = blk & 7, bg = blk >> 3;
  int g = bg & (NG-1), b = bg >> 5;
  int t = threadIdx.x;
  const float* base = x + (size_t)b*NSEQ*NC + g*16 + (t&3)*4;
  float s1 = 0.f, s2 = 0.f;
  for (int p = ch*512 + (t>>2); p < (ch+1)*512; p += 64){
    float4 v = *(const float4*)(base + (size_t)p*NC);
    s1 += v.x+v.y+v.z+v.w;
    s2 += v.x*v.x + v.y*v.y + v.z*v.z + v.w*v.w;
  }
  #pragma unroll
  for (int o = 32; o; o >>= 1){ s1 += __shfl_xor(s1, o); s2 += __shfl_xor(s2, o); }
  __shared__ float a1[4], a2[4];
  if ((t & 63) == 0){ a1[t>>6] = s1; a2[t>>6] = s2; }
  __syncthreads();
  if (t == 0){
    atomicAdd(&stats[bg*2+0], a1[0]+a1[1]+a1[2]+a1[3]);
    atomicAdd(&stats[bg*2+1], a2[0]+a2[1]+a2[2]+a2[3]);
  }
}

__global__ __launch_bounds__(256) void k_gn_apply(const float* __restrict__ x, const float* __restrict__ stats,
    const float* __restrict__ gsc, const float* __restrict__ gbi, u16* __restrict__ hn){
  const float inv_cnt = 1.f/((float)NSEQ*16.f);
  size_t total = (size_t)NM*NC/4;
  for (size_t i = (size_t)blockIdx.x*blockDim.x + threadIdx.x; i < total; i += (size_t)gridDim.x*blockDim.x){
    size_t flat = i*4;
    int c = (int)(flat & (NC-1));
    int b = (int)(flat >> 21);
    int g = c >> 4;
    float s1 = stats[(b*NG+g)*2], s2 = stats[(b*NG+g)*2+1];
    float mean = s1*inv_cnt;
    float rstd = rsqrtf(s2*inv_cnt - mean*mean + 1e-6f);
    float4 v = *(const float4*)(x + flat);
    float4 sc = *(const float4*)(gsc + c);
    float4 bi = *(const float4*)(gbi + c);
    ushort4 o;
    o.x = f2bf((v.x-mean)*rstd*sc.x + bi.x);
    o.y = f2bf((v.y-mean)*rstd*sc.y + bi.y);
    o.z = f2bf((v.z-mean)*rstd*sc.z + bi.z);
    o.w = f2bf((v.w-mean)*rstd*sc.w + bi.w);
    *(ushort4*)(hn + flat) = o;
  }
}

__global__ __launch_bounds__(256) void k_wtrans4(const float* __restrict__ wq, const float* __restrict__ wk,
    const float* __restrict__ wv, const float* __restrict__ wo,
    u16* __restrict__ wqkvT, u16* __restrict__ woT){
  int j = blockIdx.x*256 + threadIdx.x;
  int wsel = j >> 18, r = j & 262143;
  int n = r >> 9, k = r & 511;
  const float* src = wsel==0?wq : wsel==1?wk : wsel==2?wv : wo;
  u16 v = f2bf(src[k*512 + n]);
  if (wsel < 3) wqkvT[(size_t)wsel*262144 + r] = v;
  else          woT[r] = v;
}

__global__ __launch_bounds__(256) void k_sumred(const float* __restrict__ part, float* __restrict__ sums){
  int row = blockIdx.x*4 + (threadIdx.x >> 6);
  int l = threadIdx.x & 63;
  float s = part[(size_t)row*64 + l];
  #pragma unroll
  for (int o = 32; o; o >>= 1) s += __shfl_xor(s, o);
  if (l == 0) sums[row] = s;
}

__global__ __launch_bounds__(256) void k_pvred(const u16* __restrict__ op, const float* __restrict__ sums,
    u16* __restrict__ o){
  size_t i = ((size_t)blockIdx.x*256 + threadIdx.x)*8;
  int row = (int)(i >> 9);
  float inv = 1.f/sums[row];
  u32x4 a = __builtin_nontemporal_load((const u32x4*)(op + i));
  u32x4 b = __builtin_nontemporal_load((const u32x4*)(op + (size_t)NM*NC + i));
  uint32_t r[4];
  #pragma unroll
  for (int j=0;j<4;j++){
    float lo = (bfu(a[j] & 0xFFFFu) + bfu(b[j] & 0xFFFFu)) * inv;
    float hi = (__builtin_bit_cast(float, a[j] & 0xFFFF0000u) +
                __builtin_bit_cast(float, b[j] & 0xFFFF0000u)) * inv;
    r[j] = (uint32_t)f2bf(lo) | ((uint32_t)f2bf(hi) << 16);
  }
  *(uint4*)(o + i) = make_uint4(r[0], r[1], r[2], r[3]);
}

// ================= round-5 256x256 8-phase GEMM (QKV / PV / out-proj) =================
#define PH_A  { __builtin_amdgcn_sched_barrier(0); __builtin_amdgcn_s_barrier(); \
  asm volatile("s_waitcnt lgkmcnt(0)" ::: "memory"); __builtin_amdgcn_sched_barrier(0); \
  __builtin_amdgcn_s_setprio(1); }
#define PH_B  { __builtin_amdgcn_s_setprio(0); __builtin_amdgcn_sched_barrier(0); \
  __builtin_amdgcn_s_barrier(); }
#define PH_BV { __builtin_amdgcn_s_setprio(0); __builtin_amdgcn_sched_barrier(0); \
  asm volatile("s_waitcnt vmcnt(8)" ::: "memory"); __builtin_amdgcn_s_barrier(); }

template<int MODE>
__global__ __launch_bounds__(512, 2) void k_gemm8(
    const u16* __restrict__ A, const u16* __restrict__ B,
    size_t aBatch, size_t bBatch, int lda_, int ldb_, int Klen, float alpha,
    void* __restrict__ out0, void* __restrict__ out1, void* __restrict__ out2,
    const float* __restrict__ bias0, const float* __restrict__ bias1, const float* __restrict__ bias2,
    const float* __restrict__ aux1)
{
  __shared__ u16 LDS[65536];   // 128 KiB
  const size_t lda = lda_, ldb = ldb_;
  const int t = threadIdx.x;
  const int l = t & 63, w = t >> 6;
  const int wr = w >> 2, wc = w & 3;
  const int frow = l & 15, kq = l >> 4;
  const int nx = gridDim.x, ny = gridDim.y;
  int f = ((int)blockIdx.z*ny + (int)blockIdx.y)*nx + (int)blockIdx.x;
  const int nwg = nx*ny*(int)gridDim.z;
  f = (f & 7)*(nwg >> 3) + (f >> 3);
  const int bx = f % nx; const int t2 = f / nx;
  const int by = t2 % ny; const int bz = t2 / ny;
  int bb = 0, kOff = 0;
  if constexpr (MODE == 4){ bb = bz & 3; kOff = (bz >> 2)*(NSEQ/2); }
  const int brow = by*256, bcol = bx*256;

  f32x4 acc[8][4] = {};
  const int kswz = 8*(((t&7) ^ (t>>3) ^ (t>>5)) & 7);
  const u16* Ast = A + (size_t)bb*aBatch + (size_t)(brow + (t>>3))*lda + kOff + kswz;
  const u16* Bst = B + (size_t)bb*bBatch + (size_t)(bcol + (t>>3))*ldb + kOff + kswz;
  char* Lb = (char*)LDS;
  char* stD = Lb + t*16;

  auto stage = [&](int buf, int isB, int half, int kt){
    const u16* s = (isB ? Bst : Ast) + (size_t)(half*128)*(isB?ldb:lda) + (size_t)kt*64;
    char* d = stD + buf*65536 + isB*32768 + half*16384;
    gll16(s, d);
    gll16(s + (size_t)64*(isB?ldb:lda), d + 8192);
  };
  auto ldA = [&](int buf, int quad, bf16x8* dst){
    const char* base = Lb + buf*65536 + wr*16384;
    #pragma unroll
    for (int mf=0; mf<4; mf++)
      #pragma unroll
      for (int ks=0; ks<2; ks++){
        int rl = quad*64 + mf*16 + frow;
        int byte = (rl*128 + ks*64 + kq*16) ^ SWZ(rl);
        dst[mf*2+ks] = *(const bf16x8*)(base + byte);
      }
  };
  auto ldB = [&](int buf, int qc, bf16x8* dst){
    const char* base = Lb + buf*65536 + 32768 + (wc>>1)*16384;
    #pragma unroll
    for (int nf=0; nf<2; nf++)
      #pragma unroll
      for (int ks=0; ks<2; ks++){
        int rl = (wc&1)*64 + 4*frow + qc*2 + nf;
        int byte = (rl*128 + ks*64 + kq*16) ^ SWZ(rl);
        dst[nf*2+ks] = *(const bf16x8*)(base + byte);
      }
  };
  auto quad = [&](int qr, int qc, const bf16x8* af, const bf16x8* bf){
    #pragma unroll
    for (int mf=0; mf<4; mf++)
      #pragma unroll
      for (int nf=0; nf<2; nf++)
        #pragma unroll
        for (int ks=0; ks<2; ks++)
          acc[qr*4+mf][qc*2+nf] = MFMA_(af[mf*2+ks], bf[nf*2+ks], acc[qr*4+mf][qc*2+nf]);
  };

  bf16x8 af[8], b0[4], b1[4];
  const int NT = Klen >> 6;
  stage(0,0,0,0); stage(0,0,1,0); stage(0,1,0,0); stage(0,1,1,0);
  stage(1,0,0,1); stage(1,0,1,1); stage(1,1,0,1); stage(1,1,1,1);
  asm volatile("s_waitcnt vmcnt(8)" ::: "memory");
  __builtin_amdgcn_s_barrier();

  for (int i = 0; i < (NT>>1); i++){
    const int st0 = (2*i+2 < NT) ? 2*i+2 : NT-1;
    const int st1 = (2*i+3 < NT) ? 2*i+3 : NT-1;
    ldA(0,0,af); ldB(0,0,b0);
    PH_A; quad(0,0,af,b0); PH_B;
    ldB(0,1,b1);
    PH_A; quad(0,1,af,b1); PH_B;
    ldA(0,1,af);
    stage(0,1,0,st0); stage(0,1,1,st0);
    PH_A; quad(1,0,af,b0); PH_B;
    stage(0,0,0,st0); stage(0,0,1,st0);
    PH_A; quad(1,1,af,b1); PH_BV;
    ldA(1,0,af); ldB(1,0,b0);
    PH_A; quad(0,0,af,b0); PH_B;
    ldB(1,1,b1);
    PH_A; quad(0,1,af,b1); PH_B;
    ldA(1,1,af);
    stage(1,1,0,st1); stage(1,1,1,st1);
    PH_A; quad(1,0,af,b0); PH_B;
    stage(1,0,0,st1); stage(1,0,1,st1);
    PH_A; quad(1,1,af,b1); PH_BV;
  }

  const int col4 = wc*64 + 4*frow;
  if constexpr (MODE==0){
    const int seg = bcol >> 9;
    const int colr = (bcol & 511) + col4;
    if (seg < 2){
      u16* dq = (u16*)(seg==0 ? out0 : out1);
      const float* bp = seg==0 ? bias0 : bias1;
      const float4 bi = *(const float4*)(bp + colr);
      #pragma unroll
      for (int m=0;m<8;m++){
        #pragma unroll
        for (int r=0;r<4;r++){
          const int rr = brow + wr*128 + m*16 + kq*4 + r;
          u32x2 wv;
          wv[0] = pk2(acc[m][0][r]+bi.x, acc[m][1][r]+bi.y);
          wv[1] = pk2(acc[m][2][r]+bi.z, acc[m][3][r]+bi.w);
          *(u32x2*)&dq[(size_t)rr*NC + colr] = wv;
        }
      }
    } else {
      const float4 bi = *(const float4*)(bias2 + colr);
      const float bvs[4] = {bi.x, bi.y, bi.z, bi.w};
      #pragma unroll
      for (int m=0;m<8;m++){
        const int rr0 = brow + wr*128 + m*16 + kq*4;
        const int b = rr0 >> 12, sq = rr0 & 4095;
        #pragma unroll
        for (int n=0;n<4;n++){
          u32x2 wv;
          wv[0] = pk2(acc[m][n][0]+bvs[n], acc[m][n][1]+bvs[n]);
          wv[1] = pk2(acc[m][n][2]+bvs[n], acc[m][n][3]+bvs[n]);
          *(u32x2*)&((u16*)out2)[((size_t)(b*NC + colr + n) << 12) + sq] = wv;
        }
      }
    }
  } else if constexpr (MODE==4){
    const int sp = bz >> 2;
    u16* op = (u16*)out0 + (size_t)sp*NM*NC + (size_t)bb*NSEQ*NC;
    #pragma unroll
    for (int m=0;m<8;m++){
      #pragma unroll
      for (int r=0;r<4;r++){
        const int rr = brow + wr*128 + m*16 + kq*4 + r;
        u32x2 wv;
        wv[0] = pk2(acc[m][0][r], acc[m][1][r]);
        wv[1] = pk2(acc[m][2][r], acc[m][3][r]);
        __builtin_nontemporal_store(wv, (u32x2*)&op[(size_t)rr*NC + bcol + col4]);
      }
    }
  } else {
    const int c = bcol + col4;
    const float4 bi = *(const float4*)(bias0 + c);
    #pragma unroll
    for (int m=0;m<8;m++){
      #pragma unroll
      for (int r=0;r<4;r++){
        const int rr = brow + wr*128 + m*16 + kq*4 + r;
        const float4 res = *(const float4*)(aux1 + (size_t)rr*NC + c);
        float4 ov;
        ov.x = acc[m][0][r] + bi.x + res.x;
        ov.y = acc[m][1][r] + bi.y + res.y;
        ov.z = acc[m][2][r] + bi.z + res.z;
        ov.w = acc[m][3][r] + bi.w + res.w;
        *(float4*)&((float*)out0)[(size_t)rr*NC + c] = ov;
      }
    }
  }
}

// ================= NEW: QK^T kernel — 128x256, BK=32, ring-3, 2 blocks/CU =================
// LDS 72 KiB: B region 3x16KB @0, A region 3x8KB @49152.
// Swizzle: phys slot p(rl,kq) = P(rl)^kq, P = (rl0^rl2)<<2 | (rl1^rl3)<<1 | (rl2^rl4);
// addr = (rl>>1)*128 + p*16. 2-way (free) for stride-1 A reads AND stride-4 B reads;
// staging decodes the inverse so gll16 dest stays linear (rule #21).
#define NTQ 16   // K=512 / BK=32

__device__ __forceinline__ int dec_rl(int L, int p){ return 2*L + ((p>>2) ^ ((L>>1)&1)); }
__device__ __forceinline__ int dec_kq(int L, int p){
  int P01 = ((((L)&1)^((L>>2)&1))<<1) | (((L>>1)&1)^((L>>3)&1));
  return (p&3) ^ P01;
}
__device__ __forceinline__ int swz_off(int rl, int kq){
  int Pq = (((rl&1)^((rl>>2)&1))<<2) | ((((rl>>1)&1)^((rl>>3)&1))<<1) | (((rl>>2)&1)^((rl>>4)&1));
  return ((rl>>1)<<7) + ((Pq ^ kq)<<4);
}

__global__ __launch_bounds__(512, 4) void k_qkt(
    const u16* __restrict__ Q, const u16* __restrict__ Km,
    u16* __restrict__ P, float* __restrict__ partsum, float alpha)
{
  __shared__ u16 LDS[36864];   // 72 KiB
  char* Lb = (char*)LDS;
  const int t = threadIdx.x;
  const int l = t & 63, w = t >> 6;
  const int wr = w >> 2, wc = w & 3;
  const int frow = l & 15, kq = l >> 4;
  // XCD remap (nwg=2048)
  int f = ((int)blockIdx.z*32 + (int)blockIdx.y)*16 + (int)blockIdx.x;
  f = (f & 7)*256 + (f >> 3);
  const int bx = f & 15; const int t2 = f >> 4;
  const int by = t2 & 31; const int bb = t2 >> 5;
  const int brow = by*128, bcol = bx*256;

  // staging source decode (per-thread constants)
  const int pA = t & 7;
  const int LA = t >> 3;                 // A slab: 64 lines
  const int LB0 = t >> 3, LB1 = 64 + (t >> 3);
  const int rlA  = dec_rl(LA, pA),  kqA  = dec_kq(LA, pA);
  const int rlB0 = dec_rl(LB0, pA), kqB0 = dec_kq(LB0, pA);
  const int rlB1 = dec_rl(LB1, pA), kqB1 = dec_kq(LB1, pA);
  const u16* Ap  = Q  + (size_t)bb*NSEQ*NC + (size_t)(brow + rlA )*NC + kqA*8;
  const u16* Bp0 = Km + (size_t)bb*NSEQ*NC + (size_t)(bcol + rlB0)*NC + kqB0*8;
  const u16* Bp1 = Km + (size_t)bb*NSEQ*NC + (size_t)(bcol + rlB1)*NC + kqB1*8;

  auto stage = [&](int buf, int kt){
    const size_t ko = (size_t)kt*32;
    gll16(Bp0 + ko, Lb + buf*16384 + t*16);
    gll16(Bp1 + ko, Lb + buf*16384 + 8192 + t*16);
    gll16(Ap  + ko, Lb + 49152 + buf*8192 + t*16);
  };

  // read offsets (per-lane constants)
  int offA[4], offB[4];
  #pragma unroll
  for (int m=0;m<4;m++) offA[m] = swz_off(wr*64 + m*16 + frow, kq);
  #pragma unroll
  for (int c=0;c<4;c++) offB[c] = swz_off(wc*64 + 4*frow + c, kq);

  f32x4 acc[4][4] = {};

  auto body = [&](int buf, int s){
    bf16x8 a4[4], b4[4];
    #pragma unroll
    for (int m=0;m<4;m++) a4[m] = *(const bf16x8*)(Lb + 49152 + buf*8192 + offA[m]);
    #pragma unroll
    for (int c=0;c<4;c++) b4[c] = *(const bf16x8*)(Lb + buf*16384 + offB[c]);
    const bool doStage = (s + 2 < NTQ);
    if (doStage){ int nb = buf+2; if (nb>=3) nb-=3; stage(nb, s+2); }
    asm volatile("s_waitcnt lgkmcnt(0)" ::: "memory");
    __builtin_amdgcn_sched_barrier(0);
    __builtin_amdgcn_s_setprio(1);
    #pragma unroll
    for (int m=0;m<4;m++)
      #pragma unroll
      for (int c=0;c<4;c++)
        acc[m][c] = MFMA_(a4[m], b4[c], acc[m][c]);
    __builtin_amdgcn_s_setprio(0);
    __builtin_amdgcn_sched_barrier(0);
    if (s + 1 < NTQ){
      if (doStage) asm volatile("s_waitcnt vmcnt(3)" ::: "memory");
      else         asm volatile("s_waitcnt vmcnt(0)" ::: "memory");
      __builtin_amdgcn_s_barrier();
    }
  };

  stage(0, 0); stage(1, 1);
  asm volatile("s_waitcnt vmcnt(3)" ::: "memory");
  __builtin_amdgcn_s_barrier();

  #pragma unroll
  for (int i = 0; i < 5; i++){
    body(0, i*3);
    body(1, i*3+1);
    body(2, i*3+2);
  }
  body(0, 15);   // NTQ-1, buf (NTQ-1)%3 == 0

  // epilogue: exp + packed nt-store + per-(row, 64col-chunk) partial sums
  const int col4 = bcol + wc*64 + 4*frow;
  u16* Pp = P + (size_t)bb*NSEQ*NSEQ;
  #pragma unroll
  for (int m=0;m<4;m++){
    #pragma unroll
    for (int r=0;r<4;r++){
      const int rr = brow + wr*64 + m*16 + kq*4 + r;
      float e0 = __expf(alpha*acc[m][0][r]);
      float e1 = __expf(alpha*acc[m][1][r]);
      float e2 = __expf(alpha*acc[m][2][r]);
      float e3 = __expf(alpha*acc[m][3][r]);
      u32x2 wv; wv[0] = pk2(e0, e1); wv[1] = pk2(e2, e3);
      __builtin_nontemporal_store(wv, (u32x2*)&Pp[(size_t)rr*NSEQ + col4]);
      float rs = bfu(wv[0] & 0xFFFFu) + bfu(wv[0] >> 16) + bfu(wv[1] & 0xFFFFu) + bfu(wv[1] >> 16);
      rs += __shfl_xor(rs, 1); rs += __shfl_xor(rs, 2);
      rs += __shfl_xor(rs, 4); rs += __shfl_xor(rs, 8);
      if (frow == 0)
        partsum[((size_t)bb*NSEQ + rr)*64 + bx*4 + wc] = rs;
    }
  }
}

extern "C" void kernel_launch(void* const* d_in, const int* in_sizes, int n_in,
                              void* d_out, int out_size, void* d_ws, size_t ws_size,
                              hipStream_t stream){
  const float* x   = (const float*)d_in[0];
  const float* gsc = (const float*)d_in[1];
  const float* gbi = (const float*)d_in[2];
  const float* wq  = (const float*)d_in[3];
  const float* bq  = (const float*)d_in[4];
  const float* wk  = (const float*)d_in[5];
  const float* bk  = (const float*)d_in[6];
  const float* wv  = (const float*)d_in[7];
  const float* bv  = (const float*)d_in[8];
  const float* wo  = (const float*)d_in[9];
  const float* bo  = (const float*)d_in[10];
  float* out = (float*)d_out;

  char* wsp = (char*)d_ws;
  size_t off = 0;
  auto alloc = [&](size_t bytes)->void*{ void* p = wsp + off; off += (bytes + 255) & ~(size_t)255; return p; };
  float* stats   = (float*)alloc((size_t)NB*NG*2*sizeof(float));
  float* sums    = (float*)alloc((size_t)NM*sizeof(float));
  float* partsum = (float*)alloc((size_t)NM*64*sizeof(float));
  u16* hn    = (u16*)alloc((size_t)NM*NC*2);
  u16* wqkvT = (u16*)alloc((size_t)3*NC*NC*2);
  u16* woT   = (u16*)alloc((size_t)NC*NC*2);
  u16* q     = (u16*)alloc((size_t)NM*NC*2);
  u16* kk    = (u16*)alloc((size_t)NM*NC*2);
  u16* vT    = (u16*)alloc((size_t)NM*NC*2);
  u16* o     = (u16*)alloc((size_t)NM*NC*2);
  u16* P     = (u16*)alloc((size_t)NB*NSEQ*NSEQ*2);
  u16* opart = q;  // PV split-K partials [2][NM][NC] alias dead q+kk (32 MiB)

  k_zero<<<1,256,0,stream>>>(stats, NB*NG*2);
  k_gn_stats<<<NB*NG*8,256,0,stream>>>(x, stats);
  k_gn_apply<<<2048,256,0,stream>>>(x, stats, gsc, gbi, hn);
  k_wtrans4<<<4096,256,0,stream>>>(wq, wk, wv, wo, wqkvT, woT);

  // QKV projection: M=16384, N=1536, K=512 (round-5 kernel)
  k_gemm8<0><<<dim3(6,64,1),512,0,stream>>>(hn, wqkvT, 0, 0, NC, NC, NC, 1.f,
      q, kk, vT, bq, bk, bv, nullptr);

  const float scale = 0.044194173824159216f;  // 512^-0.5
  // QK^T: NEW kernel — 128x256 tile, 2 blocks/CU, ring-3 counted vmcnt
  k_qkt<<<dim3(16,32,NB),512,0,stream>>>(q, kk, P, partsum, scale);
  k_sumred<<<NM/4,256,0,stream>>>(partsum, sums);
  // PV split-K=2: M=4096, N=512, Klen=2048 (round-5 kernel)
  k_gemm8<4><<<dim3(2,16,8),512,0,stream>>>(P, vT,
      (size_t)NSEQ*NSEQ, (size_t)NC*NSEQ, NSEQ, NSEQ, NSEQ/2, 1.f,
      opart, nullptr, nullptr, nullptr, nullptr, nullptr, nullptr);
  k_pvred<<<NM*NC/8/256,256,0,stream>>>(opart, sums, o);
  // output projection + bias + residual: M=16384, N=512, K=512 (round-5 kernel)
  k_gemm8<3><<<dim3(2,64,1),512,0,stream>>>(o, woT, 0, 0, NC, NC, NC, 1.f,
      out, nullptr, nullptr, bo, nullptr, nullptr, x);
}

// Round 9
// 247.780 us; speedup vs baseline: 6.8918x; 1.0578x over previous
//
#include <hip/hip_runtime.h>
#include <stdint.h>

typedef unsigned short u16;
typedef __bf16 bf16x8 __attribute__((ext_vector_type(8)));
typedef float f32x4 __attribute__((ext_vector_type(4)));
typedef uint32_t u32x2 __attribute__((ext_vector_type(2)));
typedef uint32_t u32x4 __attribute__((ext_vector_type(4)));

#define NB 4
#define NC 512
#define NG 32
#define NSEQ 4096
#define NM (NB*NSEQ)

#define MFMA_(a,b,c) __builtin_amdgcn_mfma_f32_16x16x32_bf16(a,b,c,0,0,0)
#define SWZ(rl) (((((rl) ^ ((rl)>>2)) & 7)) << 4)

__device__ __forceinline__ u16 f2bf(float f){
  uint32_t u = __builtin_bit_cast(uint32_t, f);
  u += 0x7FFFu + ((u >> 16) & 1u);
  return (u16)(u >> 16);
}
__device__ __forceinline__ float bfu(uint32_t lo16){
  return __builtin_bit_cast(float, lo16 << 16);
}
__device__ __forceinline__ uint32_t pk2(float a, float b){
  return (uint32_t)f2bf(a) | ((uint32_t)f2bf(b) << 16);
}

__device__ __forceinline__ void gll16(const void* g, void* l){
  __builtin_amdgcn_global_load_lds(
      (const __attribute__((address_space(1))) void*)g,
      (__attribute__((address_space(3))) void*)l, 16, 0, 0);
}

__global__ void k_zero(float* p, int n){
  int i = blockIdx.x*blockDim.x + threadIdx.x;
  if (i < n) p[i] = 0.f;
}

__global__ __launch_bounds__(256) void k_gn_stats(const float* __restrict__ x, float* __restrict__ stats){
  int blk = blockIdx.x;
  int ch = blk & 7, bg = blk >> 3;
  int g = bg & (NG-1), b = bg >> 5;
  int t = threadIdx.x;
  const float* base = x + (size_t)b*NSEQ*NC + g*16 + (t&3)*4;
  float s1 = 0.f, s2 = 0.f;
  for (int p = ch*512 + (t>>2); p < (ch+1)*512; p += 64){
    float4 v = *(const float4*)(base + (size_t)p*NC);
    s1 += v.x+v.y+v.z+v.w;
    s2 += v.x*v.x + v.y*v.y + v.z*v.z + v.w*v.w;
  }
  #pragma unroll
  for (int o = 32; o; o >>= 1){ s1 += __shfl_xor(s1, o); s2 += __shfl_xor(s2, o); }
  __shared__ float a1[4], a2[4];
  if ((t & 63) == 0){ a1[t>>6] = s1; a2[t>>6] = s2; }
  __syncthreads();
  if (t == 0){
    atomicAdd(&stats[bg*2+0], a1[0]+a1[1]+a1[2]+a1[3]);
    atomicAdd(&stats[bg*2+1], a2[0]+a2[1]+a2[2]+a2[3]);
  }
}

__global__ __launch_bounds__(256) void k_gn_apply(const float* __restrict__ x, const float* __restrict__ stats,
    const float* __restrict__ gsc, const float* __restrict__ gbi, u16* __restrict__ hn){
  const float inv_cnt = 1.f/((float)NSEQ*16.f);
  size_t total = (size_t)NM*NC/4;
  for (size_t i = (size_t)blockIdx.x*blockDim.x + threadIdx.x; i < total; i += (size_t)gridDim.x*blockDim.x){
    size_t flat = i*4;
    int c = (int)(flat & (NC-1));
    int b = (int)(flat >> 21);
    int g = c >> 4;
    float s1 = stats[(b*NG+g)*2], s2 = stats[(b*NG+g)*2+1];
    float mean = s1*inv_cnt;
    float rstd = rsqrtf(s2*inv_cnt - mean*mean + 1e-6f);
    float4 v = *(const float4*)(x + flat);
    float4 sc = *(const float4*)(gsc + c);
    float4 bi = *(const float4*)(gbi + c);
    ushort4 o;
    o.x = f2bf((v.x-mean)*rstd*sc.x + bi.x);
    o.y = f2bf((v.y-mean)*rstd*sc.y + bi.y);
    o.z = f2bf((v.z-mean)*rstd*sc.z + bi.z);
    o.w = f2bf((v.w-mean)*rstd*sc.w + bi.w);
    *(ushort4*)(hn + flat) = o;
  }
}

__global__ __launch_bounds__(256) void k_wtrans4(const float* __restrict__ wq, const float* __restrict__ wk,
    const float* __restrict__ wv, const float* __restrict__ wo,
    u16* __restrict__ wqkvT, u16* __restrict__ woT){
  int j = blockIdx.x*256 + threadIdx.x;
  int wsel = j >> 18, r = j & 262143;
  int n = r >> 9, k = r & 511;
  const float* src = wsel==0?wq : wsel==1?wk : wsel==2?wv : wo;
  u16 v = f2bf(src[k*512 + n]);
  if (wsel < 3) wqkvT[(size_t)wsel*262144 + r] = v;
  else          woT[r] = v;
}

__global__ __launch_bounds__(256) void k_sumred(const float* __restrict__ part, float* __restrict__ sums){
  int row = blockIdx.x*4 + (threadIdx.x >> 6);
  int l = threadIdx.x & 63;
  float s = part[(size_t)row*64 + l];
  #pragma unroll
  for (int o = 32; o; o >>= 1) s += __shfl_xor(s, o);
  if (l == 0) sums[row] = s;
}

__global__ __launch_bounds__(256) void k_pvred(const u16* __restrict__ op, const float* __restrict__ sums,
    u16* __restrict__ o){
  size_t i = ((size_t)blockIdx.x*256 + threadIdx.x)*8;
  int row = (int)(i >> 9);
  float inv = 1.f/sums[row];
  u32x4 a = __builtin_nontemporal_load((const u32x4*)(op + i));
  u32x4 b = __builtin_nontemporal_load((const u32x4*)(op + (size_t)NM*NC + i));
  uint32_t r[4];
  #pragma unroll
  for (int j=0;j<4;j++){
    float lo = (bfu(a[j] & 0xFFFFu) + bfu(b[j] & 0xFFFFu)) * inv;
    float hi = (__builtin_bit_cast(float, a[j] & 0xFFFF0000u) +
                __builtin_bit_cast(float, b[j] & 0xFFFF0000u)) * inv;
    r[j] = (uint32_t)f2bf(lo) | ((uint32_t)f2bf(hi) << 16);
  }
  *(uint4*)(o + i) = make_uint4(r[0], r[1], r[2], r[3]);
}

// ================= round-5 256x256 8-phase GEMM (PV only) =================
#define PH_A  { __builtin_amdgcn_sched_barrier(0); __builtin_amdgcn_s_barrier(); \
  asm volatile("s_waitcnt lgkmcnt(0)" ::: "memory"); __builtin_amdgcn_sched_barrier(0); \
  __builtin_amdgcn_s_setprio(1); }
#define PH_B  { __builtin_amdgcn_s_setprio(0); __builtin_amdgcn_sched_barrier(0); \
  __builtin_amdgcn_s_barrier(); }
#define PH_BV { __builtin_amdgcn_s_setprio(0); __builtin_amdgcn_sched_barrier(0); \
  asm volatile("s_waitcnt vmcnt(8)" ::: "memory"); __builtin_amdgcn_s_barrier(); }

template<int MODE>
__global__ __launch_bounds__(512, 2) void k_gemm8(
    const u16* __restrict__ A, const u16* __restrict__ B,
    size_t aBatch, size_t bBatch, int lda_, int ldb_, int Klen, float alpha,
    void* __restrict__ out0,
    const float* __restrict__ aux1)
{
  __shared__ u16 LDS[65536];   // 128 KiB
  const size_t lda = lda_, ldb = ldb_;
  const int t = threadIdx.x;
  const int l = t & 63, w = t >> 6;
  const int wr = w >> 2, wc = w & 3;
  const int frow = l & 15, kq = l >> 4;
  const int nx = gridDim.x, ny = gridDim.y;
  int f = ((int)blockIdx.z*ny + (int)blockIdx.y)*nx + (int)blockIdx.x;
  const int nwg = nx*ny*(int)gridDim.z;
  f = (f & 7)*(nwg >> 3) + (f >> 3);
  const int bx = f % nx; const int t2 = f / nx;
  const int by = t2 % ny; const int bz = t2 / ny;
  int bb = 0, kOff = 0;
  if constexpr (MODE == 4){ bb = bz & 3; kOff = (bz >> 2)*(NSEQ/2); }
  const int brow = by*256, bcol = bx*256;

  f32x4 acc[8][4] = {};
  const int kswz = 8*(((t&7) ^ (t>>3) ^ (t>>5)) & 7);
  const u16* Ast = A + (size_t)bb*aBatch + (size_t)(brow + (t>>3))*lda + kOff + kswz;
  const u16* Bst = B + (size_t)bb*bBatch + (size_t)(bcol + (t>>3))*ldb + kOff + kswz;
  char* Lb = (char*)LDS;
  char* stD = Lb + t*16;

  auto stage = [&](int buf, int isB, int half, int kt){
    const u16* s = (isB ? Bst : Ast) + (size_t)(half*128)*(isB?ldb:lda) + (size_t)kt*64;
    char* d = stD + buf*65536 + isB*32768 + half*16384;
    gll16(s, d);
    gll16(s + (size_t)64*(isB?ldb:lda), d + 8192);
  };
  auto ldA = [&](int buf, int quad, bf16x8* dst){
    const char* base = Lb + buf*65536 + wr*16384;
    #pragma unroll
    for (int mf=0; mf<4; mf++)
      #pragma unroll
      for (int ks=0; ks<2; ks++){
        int rl = quad*64 + mf*16 + frow;
        int byte = (rl*128 + ks*64 + kq*16) ^ SWZ(rl);
        dst[mf*2+ks] = *(const bf16x8*)(base + byte);
      }
  };
  auto ldB = [&](int buf, int qc, bf16x8* dst){
    const char* base = Lb + buf*65536 + 32768 + (wc>>1)*16384;
    #pragma unroll
    for (int nf=0; nf<2; nf++)
      #pragma unroll
      for (int ks=0; ks<2; ks++){
        int rl = (wc&1)*64 + 4*frow + qc*2 + nf;
        int byte = (rl*128 + ks*64 + kq*16) ^ SWZ(rl);
        dst[nf*2+ks] = *(const bf16x8*)(base + byte);
      }
  };
  auto quad = [&](int qr, int qc, const bf16x8* af, const bf16x8* bf){
    #pragma unroll
    for (int mf=0; mf<4; mf++)
      #pragma unroll
      for (int nf=0; nf<2; nf++)
        #pragma unroll
        for (int ks=0; ks<2; ks++)
          acc[qr*4+mf][qc*2+nf] = MFMA_(af[mf*2+ks], bf[nf*2+ks], acc[qr*4+mf][qc*2+nf]);
  };

  bf16x8 af[8], b0[4], b1[4];
  const int NT = Klen >> 6;
  stage(0,0,0,0); stage(0,0,1,0); stage(0,1,0,0); stage(0,1,1,0);
  stage(1,0,0,1); stage(1,0,1,1); stage(1,1,0,1); stage(1,1,1,1);
  asm volatile("s_waitcnt vmcnt(8)" ::: "memory");
  __builtin_amdgcn_s_barrier();

  for (int i = 0; i < (NT>>1); i++){
    const int st0 = (2*i+2 < NT) ? 2*i+2 : NT-1;
    const int st1 = (2*i+3 < NT) ? 2*i+3 : NT-1;
    ldA(0,0,af); ldB(0,0,b0);
    PH_A; quad(0,0,af,b0); PH_B;
    ldB(0,1,b1);
    PH_A; quad(0,1,af,b1); PH_B;
    ldA(0,1,af);
    stage(0,1,0,st0); stage(0,1,1,st0);
    PH_A; quad(1,0,af,b0); PH_B;
    stage(0,0,0,st0); stage(0,0,1,st0);
    PH_A; quad(1,1,af,b1); PH_BV;
    ldA(1,0,af); ldB(1,0,b0);
    PH_A; quad(0,0,af,b0); PH_B;
    ldB(1,1,b1);
    PH_A; quad(0,1,af,b1); PH_B;
    ldA(1,1,af);
    stage(1,1,0,st1); stage(1,1,1,st1);
    PH_A; quad(1,0,af,b0); PH_B;
    stage(1,0,0,st1); stage(1,0,1,st1);
    PH_A; quad(1,1,af,b1); PH_BV;
  }

  const int col4 = wc*64 + 4*frow;
  if constexpr (MODE==4){
    const int sp = bz >> 2;
    u16* op = (u16*)out0 + (size_t)sp*NM*NC + (size_t)bb*NSEQ*NC;
    #pragma unroll
    for (int m=0;m<8;m++){
      #pragma unroll
      for (int r=0;r<4;r++){
        const int rr = brow + wr*128 + m*16 + kq*4 + r;
        u32x2 wv;
        wv[0] = pk2(acc[m][0][r], acc[m][1][r]);
        wv[1] = pk2(acc[m][2][r], acc[m][3][r]);
        __builtin_nontemporal_store(wv, (u32x2*)&op[(size_t)rr*NC + bcol + col4]);
      }
    }
  }
}

// ============ verified round-8 machinery: swizzle + inverse decode ============
#define NTQ 16   // K=512 / BK=32

__device__ __forceinline__ int dec_rl(int L, int p){ return 2*L + ((p>>2) ^ ((L>>1)&1)); }
__device__ __forceinline__ int dec_kq(int L, int p){
  int P01 = ((((L)&1)^((L>>2)&1))<<1) | (((L>>1)&1)^((L>>3)&1));
  return (p&3) ^ P01;
}
__device__ __forceinline__ int swz_off(int rl, int kq){
  int Pq = (((rl&1)^((rl>>2)&1))<<2) | ((((rl>>1)&1)^((rl>>3)&1))<<1) | (((rl>>2)&1)^((rl>>4)&1));
  return ((rl>>1)<<7) + ((Pq ^ kq)<<4);
}

// ====== k_t512<MODE>: 128x256 tile, 8 waves, BK=32, ring-3, 2 blocks/CU ======
// MODE 0: QKV projection (A=hn, B=wqkvT): bias + q/k row-major + vT transposed
// MODE 1: QK^T (batched z): P = exp(alpha*acc) + per-(row,64col) partial sums
template<int MODE>
__global__ __launch_bounds__(512, 4) void k_t512(
    const u16* __restrict__ A, const u16* __restrict__ B,
    void* __restrict__ out0, void* __restrict__ out1, void* __restrict__ out2,
    float* __restrict__ partsum,
    const float* __restrict__ bias0, const float* __restrict__ bias1, const float* __restrict__ bias2,
    float alpha)
{
  __shared__ u16 LDS[36864];   // 72 KiB: B 3x16KB @0, A 3x8KB @49152
  char* Lb = (char*)LDS;
  const int t = threadIdx.x;
  const int l = t & 63, w = t >> 6;
  const int wr = w >> 2, wc = w & 3;
  const int frow = l & 15, kq = l >> 4;
  const int nx = gridDim.x, ny = gridDim.y;
  int f = ((int)blockIdx.z*ny + (int)blockIdx.y)*nx + (int)blockIdx.x;
  const int nwg = nx*ny*(int)gridDim.z;
  f = (f & 7)*(nwg >> 3) + (f >> 3);
  const int bx = f % nx; const int t2 = f / nx;
  const int by = t2 % ny; const int bb = t2 / ny;
  const int brow = by*128, bcol = bx*256;
  const size_t batchOff = (MODE==1) ? (size_t)bb*NSEQ*NC : 0;

  // staging source decode (per-thread constants)
  const int pA = t & 7;
  const int LA = t >> 3;
  const int LB0 = t >> 3, LB1 = 64 + (t >> 3);
  const int rlA  = dec_rl(LA, pA),  kqA  = dec_kq(LA, pA);
  const int rlB0 = dec_rl(LB0, pA), kqB0 = dec_kq(LB0, pA);
  const int rlB1 = dec_rl(LB1, pA), kqB1 = dec_kq(LB1, pA);
  const u16* Ap  = A + batchOff + (size_t)(brow + rlA )*NC + kqA*8;
  const u16* Bp0 = B + batchOff + (size_t)(bcol + rlB0)*NC + kqB0*8;
  const u16* Bp1 = B + batchOff + (size_t)(bcol + rlB1)*NC + kqB1*8;

  auto stage = [&](int buf, int kt){
    const size_t ko = (size_t)kt*32;
    gll16(Bp0 + ko, Lb + buf*16384 + t*16);
    gll16(Bp1 + ko, Lb + buf*16384 + 8192 + t*16);
    gll16(Ap  + ko, Lb + 49152 + buf*8192 + t*16);
  };

  int offA[4], offB[4];
  #pragma unroll
  for (int m=0;m<4;m++) offA[m] = swz_off(wr*64 + m*16 + frow, kq);
  #pragma unroll
  for (int c=0;c<4;c++) offB[c] = swz_off(wc*64 + 4*frow + c, kq);

  f32x4 acc[4][4] = {};

  auto body = [&](int buf, int s){
    bf16x8 a4[4], b4[4];
    #pragma unroll
    for (int m=0;m<4;m++) a4[m] = *(const bf16x8*)(Lb + 49152 + buf*8192 + offA[m]);
    #pragma unroll
    for (int c=0;c<4;c++) b4[c] = *(const bf16x8*)(Lb + buf*16384 + offB[c]);
    const bool doStage = (s + 2 < NTQ);
    if (doStage){ int nb = buf+2; if (nb>=3) nb-=3; stage(nb, s+2); }
    asm volatile("s_waitcnt lgkmcnt(0)" ::: "memory");
    __builtin_amdgcn_sched_barrier(0);
    __builtin_amdgcn_s_setprio(1);
    #pragma unroll
    for (int m=0;m<4;m++)
      #pragma unroll
      for (int c=0;c<4;c++)
        acc[m][c] = MFMA_(a4[m], b4[c], acc[m][c]);
    __builtin_amdgcn_s_setprio(0);
    __builtin_amdgcn_sched_barrier(0);
    if (s + 1 < NTQ){
      if (doStage) asm volatile("s_waitcnt vmcnt(3)" ::: "memory");
      else         asm volatile("s_waitcnt vmcnt(0)" ::: "memory");
      __builtin_amdgcn_s_barrier();
    }
  };

  stage(0, 0); stage(1, 1);
  asm volatile("s_waitcnt vmcnt(3)" ::: "memory");
  __builtin_amdgcn_s_barrier();

  #pragma unroll
  for (int i = 0; i < 5; i++){
    body(0, i*3);
    body(1, i*3+1);
    body(2, i*3+2);
  }
  body(0, 15);

  // ---------------- epilogue ----------------
  const int col4 = wc*64 + 4*frow;
  if constexpr (MODE==0){
    const int seg = bcol >> 9;                 // 256-wide tile lies in one 512-seg
    const int colr = (bcol & 511) + col4;
    if (seg < 2){
      u16* dq = (u16*)(seg==0 ? out0 : out1);
      const float* bp = seg==0 ? bias0 : bias1;
      const float4 bi = *(const float4*)(bp + colr);
      #pragma unroll
      for (int m=0;m<4;m++){
        #pragma unroll
        for (int r=0;r<4;r++){
          const int rr = brow + wr*64 + m*16 + kq*4 + r;
          u32x2 wv;
          wv[0] = pk2(acc[m][0][r]+bi.x, acc[m][1][r]+bi.y);
          wv[1] = pk2(acc[m][2][r]+bi.z, acc[m][3][r]+bi.w);
          *(u32x2*)&dq[(size_t)rr*NC + colr] = wv;
        }
      }
    } else {
      const float4 bi = *(const float4*)(bias2 + colr);
      const float bvs[4] = {bi.x, bi.y, bi.z, bi.w};
      #pragma unroll
      for (int m=0;m<4;m++){
        const int rr0 = brow + wr*64 + m*16 + kq*4;
        const int b = rr0 >> 12, sq = rr0 & 4095;
        #pragma unroll
        for (int n=0;n<4;n++){
          u32x2 wv;
          wv[0] = pk2(acc[m][n][0]+bvs[n], acc[m][n][1]+bvs[n]);
          wv[1] = pk2(acc[m][n][2]+bvs[n], acc[m][n][3]+bvs[n]);
          *(u32x2*)&((u16*)out2)[((size_t)(b*NC + colr + n) << 12) + sq] = wv;
        }
      }
    }
  } else {
    u16* Pp = (u16*)out0 + (size_t)bb*NSEQ*NSEQ;
    const int colg = bcol + col4;
    #pragma unroll
    for (int m=0;m<4;m++){
      #pragma unroll
      for (int r=0;r<4;r++){
        const int rr = brow + wr*64 + m*16 + kq*4 + r;
        float e0 = __expf(alpha*acc[m][0][r]);
        float e1 = __expf(alpha*acc[m][1][r]);
        float e2 = __expf(alpha*acc[m][2][r]);
        float e3 = __expf(alpha*acc[m][3][r]);
        u32x2 wv; wv[0] = pk2(e0, e1); wv[1] = pk2(e2, e3);
        __builtin_nontemporal_store(wv, (u32x2*)&Pp[(size_t)rr*NSEQ + colg]);
        float rs = bfu(wv[0] & 0xFFFFu) + bfu(wv[0] >> 16) + bfu(wv[1] & 0xFFFFu) + bfu(wv[1] >> 16);
        rs += __shfl_xor(rs, 1); rs += __shfl_xor(rs, 2);
        rs += __shfl_xor(rs, 4); rs += __shfl_xor(rs, 8);
        if (frow == 0)
          partsum[((size_t)bb*NSEQ + rr)*64 + bx*4 + wc] = rs;
      }
    }
  }
}

// ====== k_t256o: out-projection — 128x128 tile, 4 waves, BK=32, ring-3, 48KB ======
__global__ __launch_bounds__(256, 3) void k_t256o(
    const u16* __restrict__ A, const u16* __restrict__ B,
    float* __restrict__ out, const float* __restrict__ bias, const float* __restrict__ res)
{
  __shared__ u16 LDS[24576];   // 48 KiB: 3 bufs x (A 8KB + B 8KB)
  char* Lb = (char*)LDS;
  const int t = threadIdx.x;
  const int l = t & 63, w = t >> 6;
  const int wr = w >> 1, wc = w & 1;
  const int frow = l & 15, kq = l >> 4;
  // XCD remap: grid (4,128) -> nwg=512
  int f = (int)blockIdx.y*4 + (int)blockIdx.x;
  f = (f & 7)*64 + (f >> 3);
  const int bx = f & 3; const int by = f >> 2;
  const int brow = by*128, bcol = bx*128;

  const int pA = t & 7;
  const int L0 = t >> 3;          // 0..31
  const int rl0 = dec_rl(L0, pA),      kq0 = dec_kq(L0, pA);
  const int rl1 = dec_rl(L0+32, pA),   kq1 = dec_kq(L0+32, pA);
  const u16* Ap0 = A + (size_t)(brow + rl0)*NC + kq0*8;
  const u16* Ap1 = A + (size_t)(brow + rl1)*NC + kq1*8;
  const u16* Bp0 = B + (size_t)(bcol + rl0)*NC + kq0*8;
  const u16* Bp1 = B + (size_t)(bcol + rl1)*NC + kq1*8;

  auto stage = [&](int buf, int kt){
    const size_t ko = (size_t)kt*32;
    gll16(Ap0 + ko, Lb + buf*16384 + t*16);
    gll16(Ap1 + ko, Lb + buf*16384 + 4096 + t*16);
    gll16(Bp0 + ko, Lb + buf*16384 + 8192 + t*16);
    gll16(Bp1 + ko, Lb + buf*16384 + 12288 + t*16);
  };

  int offA[4], offB[4];
  #pragma unroll
  for (int m=0;m<4;m++) offA[m] = swz_off(wr*64 + m*16 + frow, kq);
  #pragma unroll
  for (int c=0;c<4;c++) offB[c] = swz_off(wc*64 + 4*frow + c, kq);

  f32x4 acc[4][4] = {};

  auto body = [&](int buf, int s){
    bf16x8 a4[4], b4[4];
    #pragma unroll
    for (int m=0;m<4;m++) a4[m] = *(const bf16x8*)(Lb + buf*16384 + offA[m]);
    #pragma unroll
    for (int c=0;c<4;c++) b4[c] = *(const bf16x8*)(Lb + buf*16384 + 8192 + offB[c]);
    const bool doStage = (s + 2 < NTQ);
    if (doStage){ int nb = buf+2; if (nb>=3) nb-=3; stage(nb, s+2); }
    asm volatile("s_waitcnt lgkmcnt(0)" ::: "memory");
    __builtin_amdgcn_sched_barrier(0);
    __builtin_amdgcn_s_setprio(1);
    #pragma unroll
    for (int m=0;m<4;m++)
      #pragma unroll
      for (int c=0;c<4;c++)
        acc[m][c] = MFMA_(a4[m], b4[c], acc[m][c]);
    __builtin_amdgcn_s_setprio(0);
    __builtin_amdgcn_sched_barrier(0);
    if (s + 1 < NTQ){
      if (doStage) asm volatile("s_waitcnt vmcnt(4)" ::: "memory");
      else         asm volatile("s_waitcnt vmcnt(0)" ::: "memory");
      __builtin_amdgcn_s_barrier();
    }
  };

  stage(0, 0); stage(1, 1);
  asm volatile("s_waitcnt vmcnt(4)" ::: "memory");
  __builtin_amdgcn_s_barrier();

  #pragma unroll
  for (int i = 0; i < 5; i++){
    body(0, i*3);
    body(1, i*3+1);
    body(2, i*3+2);
  }
  body(0, 15);

  const int c = bcol + wc*64 + 4*frow;
  const float4 bi = *(const float4*)(bias + c);
  #pragma unroll
  for (int m=0;m<4;m++){
    #pragma unroll
    for (int r=0;r<4;r++){
      const int rr = brow + wr*64 + m*16 + kq*4 + r;
      const float4 rv = *(const float4*)(res + (size_t)rr*NC + c);
      float4 ov;
      ov.x = acc[m][0][r] + bi.x + rv.x;
      ov.y = acc[m][1][r] + bi.y + rv.y;
      ov.z = acc[m][2][r] + bi.z + rv.z;
      ov.w = acc[m][3][r] + bi.w + rv.w;
      *(float4*)&out[(size_t)rr*NC + c] = ov;
    }
  }
}

extern "C" void kernel_launch(void* const* d_in, const int* in_sizes, int n_in,
                              void* d_out, int out_size, void* d_ws, size_t ws_size,
                              hipStream_t stream){
  const float* x   = (const float*)d_in[0];
  const float* gsc = (const float*)d_in[1];
  const float* gbi = (const float*)d_in[2];
  const float* wq  = (const float*)d_in[3];
  const float* bq  = (const float*)d_in[4];
  const float* wk  = (const float*)d_in[5];
  const float* bk  = (const float*)d_in[6];
  const float* wv  = (const float*)d_in[7];
  const float* bv  = (const float*)d_in[8];
  const float* wo  = (const float*)d_in[9];
  const float* bo  = (const float*)d_in[10];
  float* out = (float*)d_out;

  char* wsp = (char*)d_ws;
  size_t off = 0;
  auto alloc = [&](size_t bytes)->void*{ void* p = wsp + off; off += (bytes + 255) & ~(size_t)255; return p; };
  float* stats   = (float*)alloc((size_t)NB*NG*2*sizeof(float));
  float* sums    = (float*)alloc((size_t)NM*sizeof(float));
  float* partsum = (float*)alloc((size_t)NM*64*sizeof(float));
  u16* hn    = (u16*)alloc((size_t)NM*NC*2);
  u16* wqkvT = (u16*)alloc((size_t)3*NC*NC*2);
  u16* woT   = (u16*)alloc((size_t)NC*NC*2);
  u16* q     = (u16*)alloc((size_t)NM*NC*2);
  u16* kk    = (u16*)alloc((size_t)NM*NC*2);
  u16* vT    = (u16*)alloc((size_t)NM*NC*2);
  u16* o     = (u16*)alloc((size_t)NM*NC*2);
  u16* P     = (u16*)alloc((size_t)NB*NSEQ*NSEQ*2);
  u16* opart = q;  // PV split-K partials [2][NM][NC] alias dead q+kk (32 MiB)

  k_zero<<<1,256,0,stream>>>(stats, NB*NG*2);
  k_gn_stats<<<NB*NG*8,256,0,stream>>>(x, stats);
  k_gn_apply<<<2048,256,0,stream>>>(x, stats, gsc, gbi, hn);
  k_wtrans4<<<4096,256,0,stream>>>(wq, wk, wv, wo, wqkvT, woT);

  // QKV projection: M=16384, N=1536, K=512 — new 2-blocks/CU structure
  k_t512<0><<<dim3(6,128,1),512,0,stream>>>(hn, wqkvT,
      q, kk, vT, nullptr, bq, bk, bv, 1.f);

  const float scale = 0.044194173824159216f;  // 512^-0.5
  // QK^T: round-8 winner (unchanged structure)
  k_t512<1><<<dim3(16,32,NB),512,0,stream>>>(q, kk,
      P, nullptr, nullptr, partsum, nullptr, nullptr, nullptr, scale);
  k_sumred<<<NM/4,256,0,stream>>>(partsum, sums);
  // PV split-K=2: 8-phase 256x256 (unchanged)
  k_gemm8<4><<<dim3(2,16,8),512,0,stream>>>(P, vT,
      (size_t)NSEQ*NSEQ, (size_t)NC*NSEQ, NSEQ, NSEQ, NSEQ/2, 1.f,
      opart, nullptr);
  k_pvred<<<NM*NC/8/256,256,0,stream>>>(opart, sums, o);
  // output projection + bias + residual: new 3-blocks/CU structure
  k_t256o<<<dim3(4,128,1),256,0,stream>>>(o, woT, out, bo, x);
}

// Round 10
// 229.170 us; speedup vs baseline: 7.4514x; 1.0812x over previous
//
#include <hip/hip_runtime.h>
#include <stdint.h>

typedef unsigned short u16;
typedef long i64;
typedef __bf16 bf16x8 __attribute__((ext_vector_type(8)));
typedef float f32x4 __attribute__((ext_vector_type(4)));
typedef uint32_t u32x2 __attribute__((ext_vector_type(2)));
typedef uint32_t u32x4 __attribute__((ext_vector_type(4)));

#define NB 4
#define NC 512
#define NG 32
#define NSEQ 4096
#define NM (NB*NSEQ)

#define MFMA_(a,b,c) __builtin_amdgcn_mfma_f32_16x16x32_bf16(a,b,c,0,0,0)
#define MFMA8_(a,b,c) __builtin_amdgcn_mfma_f32_16x16x32_fp8_fp8(a,b,c,0,0,0)
#define SWZ(rl) (((((rl) ^ ((rl)>>2)) & 7)) << 4)

__device__ __forceinline__ u16 f2bf(float f){
  uint32_t u = __builtin_bit_cast(uint32_t, f);
  u += 0x7FFFu + ((u >> 16) & 1u);
  return (u16)(u >> 16);
}
__device__ __forceinline__ float bfu(uint32_t lo16){
  return __builtin_bit_cast(float, lo16 << 16);
}
__device__ __forceinline__ uint32_t pk2(float a, float b){
  return (uint32_t)f2bf(a) | ((uint32_t)f2bf(b) << 16);
}

__device__ __forceinline__ void gll16(const void* g, void* l){
  __builtin_amdgcn_global_load_lds(
      (const __attribute__((address_space(1))) void*)g,
      (__attribute__((address_space(3))) void*)l, 16, 0, 0);
}

__global__ void k_zero(float* p, int n){
  int i = blockIdx.x*blockDim.x + threadIdx.x;
  if (i < n) p[i] = 0.f;
}

// GN pass 1: row-major read of x, per-group partial sums + bf16 copy of x.
// grid NB*64, block 256: each block 64 rows x 512 cols.
__global__ __launch_bounds__(256) void k_gn_stats2(const float* __restrict__ x,
    u16* __restrict__ xbf, float* __restrict__ stats){
  int blk = blockIdx.x;
  int b = blk >> 6, ch = blk & 63;
  int t = threadIdx.x;
  int colv = t & 127;                 // float4 col index; col = colv*4
  int r0 = ch*64 + (t >> 7);          // rows r0, r0+2, ... (32 iters)
  const float* xp = x  + (size_t)b*NSEQ*NC + (size_t)r0*NC + colv*4;
  u16* xb       = xbf + (size_t)b*NSEQ*NC + (size_t)r0*NC + colv*4;
  float s1 = 0.f, s2 = 0.f;
  #pragma unroll 4
  for (int i = 0; i < 32; i++){
    float4 v = *(const float4*)(xp + (size_t)i*2*NC);
    s1 += v.x+v.y+v.z+v.w;
    s2 += v.x*v.x+v.y*v.y+v.z*v.z+v.w*v.w;
    ushort4 o; o.x=f2bf(v.x); o.y=f2bf(v.y); o.z=f2bf(v.z); o.w=f2bf(v.w);
    *(ushort4*)(xb + (size_t)i*2*NC) = o;
  }
  // 4 lanes per 16-col group
  s1 += __shfl_xor(s1,1); s2 += __shfl_xor(s2,1);
  s1 += __shfl_xor(s1,2); s2 += __shfl_xor(s2,2);
  __shared__ float ls1[4][16], ls2[4][16];
  int w = t >> 6, l = t & 63;
  if ((l & 3) == 0){ ls1[w][l>>2] = s1; ls2[w][l>>2] = s2; }
  __syncthreads();
  if (t < 32){
    int g = t;
    int wlo = g >> 4;                 // waves {0,2} hold groups 0-15; {1,3} 16-31
    float a1 = ls1[wlo][g&15] + ls1[wlo+2][g&15];
    float a2 = ls2[wlo][g&15] + ls2[wlo+2][g&15];
    atomicAdd(&stats[(b*NG+g)*2+0], a1);
    atomicAdd(&stats[(b*NG+g)*2+1], a2);
  }
}

// GN pass 2: read bf16 x-copy, normalize+affine, write hn. grid 4096.
__global__ __launch_bounds__(256) void k_gn_apply2(const u16* __restrict__ xbf,
    const float* __restrict__ stats, const float* __restrict__ gsc,
    const float* __restrict__ gbi, u16* __restrict__ hn){
  const float inv_cnt = 1.f/((float)NSEQ*16.f);
  size_t i = ((size_t)blockIdx.x*256 + threadIdx.x)*8;
  int c = (int)(i & 511);
  int b = (int)(i >> 21);
  int g = c >> 4;
  float s1 = stats[(b*NG+g)*2], s2 = stats[(b*NG+g)*2+1];
  float mean = s1*inv_cnt;
  float rstd = rsqrtf(s2*inv_cnt - mean*mean + 1e-6f);
  u32x4 v = *(const u32x4*)(xbf + i);
  float4 scA = *(const float4*)(gsc + c), scB = *(const float4*)(gsc + c + 4);
  float4 biA = *(const float4*)(gbi + c), biB = *(const float4*)(gbi + c + 4);
  const float sc[8] = {scA.x,scA.y,scA.z,scA.w,scB.x,scB.y,scB.z,scB.w};
  const float bi[8] = {biA.x,biA.y,biA.z,biA.w,biB.x,biB.y,biB.z,biB.w};
  u32x4 o;
  #pragma unroll
  for (int j = 0; j < 4; j++){
    float lo = bfu(v[j] & 0xFFFFu);
    float hi = __builtin_bit_cast(float, v[j] & 0xFFFF0000u);
    o[j] = pk2((lo-mean)*rstd*sc[2*j] + bi[2*j], (hi-mean)*rstd*sc[2*j+1] + bi[2*j+1]);
  }
  *(u32x4*)(hn + i) = o;
}

__global__ __launch_bounds__(256) void k_wtrans4(const float* __restrict__ wq, const float* __restrict__ wk,
    const float* __restrict__ wv, const float* __restrict__ wo,
    u16* __restrict__ wqkvT, u16* __restrict__ woT){
  int j = blockIdx.x*256 + threadIdx.x;
  int wsel = j >> 18, r = j & 262143;
  int n = r >> 9, k = r & 511;
  const float* src = wsel==0?wq : wsel==1?wk : wsel==2?wv : wo;
  u16 v = f2bf(src[k*512 + n]);
  if (wsel < 3) wqkvT[(size_t)wsel*262144 + r] = v;
  else          woT[r] = v;
}

__global__ __launch_bounds__(256) void k_sumred(const float* __restrict__ part, float* __restrict__ sums){
  int row = blockIdx.x*4 + (threadIdx.x >> 6);
  int l = threadIdx.x & 63;
  float s = part[(size_t)row*64 + l];
  #pragma unroll
  for (int o = 32; o; o >>= 1) s += __shfl_xor(s, o);
  if (l == 0) sums[row] = s;
}

__global__ __launch_bounds__(256) void k_pvred(const u16* __restrict__ op, const float* __restrict__ sums,
    u16* __restrict__ o){
  size_t i = ((size_t)blockIdx.x*256 + threadIdx.x)*8;
  int row = (int)(i >> 9);
  float inv = 1.f/sums[row];
  u32x4 a = __builtin_nontemporal_load((const u32x4*)(op + i));
  u32x4 b = __builtin_nontemporal_load((const u32x4*)(op + (size_t)NM*NC + i));
  uint32_t r[4];
  #pragma unroll
  for (int j=0;j<4;j++){
    float lo = (bfu(a[j] & 0xFFFFu) + bfu(b[j] & 0xFFFFu)) * inv;
    float hi = (__builtin_bit_cast(float, a[j] & 0xFFFF0000u) +
                __builtin_bit_cast(float, b[j] & 0xFFFF0000u)) * inv;
    r[j] = (uint32_t)f2bf(lo) | ((uint32_t)f2bf(hi) << 16);
  }
  *(uint4*)(o + i) = make_uint4(r[0], r[1], r[2], r[3]);
}

// ================= 256x256 8-phase GEMM (PV split-K) =================
#define PH_A  { __builtin_amdgcn_sched_barrier(0); __builtin_amdgcn_s_barrier(); \
  asm volatile("s_waitcnt lgkmcnt(0)" ::: "memory"); __builtin_amdgcn_sched_barrier(0); \
  __builtin_amdgcn_s_setprio(1); }
#define PH_B  { __builtin_amdgcn_s_setprio(0); __builtin_amdgcn_sched_barrier(0); \
  __builtin_amdgcn_s_barrier(); }
#define PH_BV { __builtin_amdgcn_s_setprio(0); __builtin_amdgcn_sched_barrier(0); \
  asm volatile("s_waitcnt vmcnt(8)" ::: "memory"); __builtin_amdgcn_s_barrier(); }

__global__ __launch_bounds__(512, 2) void k_gemm8pv(
    const u16* __restrict__ A, const u16* __restrict__ B,
    size_t aBatch, size_t bBatch, int lda_, int ldb_, int Klen,
    void* __restrict__ out0)
{
  __shared__ u16 LDS[65536];   // 128 KiB
  const size_t lda = lda_, ldb = ldb_;
  const int t = threadIdx.x;
  const int l = t & 63, w = t >> 6;
  const int wr = w >> 2, wc = w & 3;
  const int frow = l & 15, kq = l >> 4;
  const int nx = gridDim.x, ny = gridDim.y;
  int f = ((int)blockIdx.z*ny + (int)blockIdx.y)*nx + (int)blockIdx.x;
  const int nwg = nx*ny*(int)gridDim.z;
  f = (f & 7)*(nwg >> 3) + (f >> 3);
  const int bx = f % nx; const int t2 = f / nx;
  const int by = t2 % ny; const int bz = t2 / ny;
  const int bb = bz & 3, kOff = (bz >> 2)*(NSEQ/2);
  const int brow = by*256, bcol = bx*256;

  f32x4 acc[8][4] = {};
  const int kswz = 8*(((t&7) ^ (t>>3) ^ (t>>5)) & 7);
  const u16* Ast = A + (size_t)bb*aBatch + (size_t)(brow + (t>>3))*lda + kOff + kswz;
  const u16* Bst = B + (size_t)bb*bBatch + (size_t)(bcol + (t>>3))*ldb + kOff + kswz;
  char* Lb = (char*)LDS;
  char* stD = Lb + t*16;

  auto stage = [&](int buf, int isB, int half, int kt){
    const u16* s = (isB ? Bst : Ast) + (size_t)(half*128)*(isB?ldb:lda) + (size_t)kt*64;
    char* d = stD + buf*65536 + isB*32768 + half*16384;
    gll16(s, d);
    gll16(s + (size_t)64*(isB?ldb:lda), d + 8192);
  };
  auto ldA = [&](int buf, int quad, bf16x8* dst){
    const char* base = Lb + buf*65536 + wr*16384;
    #pragma unroll
    for (int mf=0; mf<4; mf++)
      #pragma unroll
      for (int ks=0; ks<2; ks++){
        int rl = quad*64 + mf*16 + frow;
        int byte = (rl*128 + ks*64 + kq*16) ^ SWZ(rl);
        dst[mf*2+ks] = *(const bf16x8*)(base + byte);
      }
  };
  auto ldB = [&](int buf, int qc, bf16x8* dst){
    const char* base = Lb + buf*65536 + 32768 + (wc>>1)*16384;
    #pragma unroll
    for (int nf=0; nf<2; nf++)
      #pragma unroll
      for (int ks=0; ks<2; ks++){
        int rl = (wc&1)*64 + 4*frow + qc*2 + nf;
        int byte = (rl*128 + ks*64 + kq*16) ^ SWZ(rl);
        dst[nf*2+ks] = *(const bf16x8*)(base + byte);
      }
  };
  auto quad = [&](int qr, int qc, const bf16x8* af, const bf16x8* bf){
    #pragma unroll
    for (int mf=0; mf<4; mf++)
      #pragma unroll
      for (int nf=0; nf<2; nf++)
        #pragma unroll
        for (int ks=0; ks<2; ks++)
          acc[qr*4+mf][qc*2+nf] = MFMA_(af[mf*2+ks], bf[nf*2+ks], acc[qr*4+mf][qc*2+nf]);
  };

  bf16x8 af[8], b0[4], b1[4];
  const int NT = Klen >> 6;
  stage(0,0,0,0); stage(0,0,1,0); stage(0,1,0,0); stage(0,1,1,0);
  stage(1,0,0,1); stage(1,0,1,1); stage(1,1,0,1); stage(1,1,1,1);
  asm volatile("s_waitcnt vmcnt(8)" ::: "memory");
  __builtin_amdgcn_s_barrier();

  for (int i = 0; i < (NT>>1); i++){
    const int st0 = (2*i+2 < NT) ? 2*i+2 : NT-1;
    const int st1 = (2*i+3 < NT) ? 2*i+3 : NT-1;
    ldA(0,0,af); ldB(0,0,b0);
    PH_A; quad(0,0,af,b0); PH_B;
    ldB(0,1,b1);
    PH_A; quad(0,1,af,b1); PH_B;
    ldA(0,1,af);
    stage(0,1,0,st0); stage(0,1,1,st0);
    PH_A; quad(1,0,af,b0); PH_B;
    stage(0,0,0,st0); stage(0,0,1,st0);
    PH_A; quad(1,1,af,b1); PH_BV;
    ldA(1,0,af); ldB(1,0,b0);
    PH_A; quad(0,0,af,b0); PH_B;
    ldB(1,1,b1);
    PH_A; quad(0,1,af,b1); PH_B;
    ldA(1,1,af);
    stage(1,1,0,st1); stage(1,1,1,st1);
    PH_A; quad(1,0,af,b0); PH_B;
    stage(1,0,0,st1); stage(1,0,1,st1);
    PH_A; quad(1,1,af,b1); PH_BV;
  }

  const int col4 = wc*64 + 4*frow;
  const int sp = bz >> 2;
  u16* op = (u16*)out0 + (size_t)sp*NM*NC + (size_t)bb*NSEQ*NC;
  #pragma unroll
  for (int m=0;m<8;m++){
    #pragma unroll
    for (int r=0;r<4;r++){
      const int rr = brow + wr*128 + m*16 + kq*4 + r;
      u32x2 wv;
      wv[0] = pk2(acc[m][0][r], acc[m][1][r]);
      wv[1] = pk2(acc[m][2][r], acc[m][3][r]);
      __builtin_nontemporal_store(wv, (u32x2*)&op[(size_t)rr*NC + bcol + col4]);
    }
  }
}

// ============ bf16 16B-granule swizzle machinery (QKV / out-proj) ============
#define NTQ 16   // K=512 / BK=32 (bf16 kernels)

__device__ __forceinline__ int dec_rl(int L, int p){ return 2*L + ((p>>2) ^ ((L>>1)&1)); }
__device__ __forceinline__ int dec_kq(int L, int p){
  int P01 = ((((L)&1)^((L>>2)&1))<<1) | (((L>>1)&1)^((L>>3)&1));
  return (p&3) ^ P01;
}
__device__ __forceinline__ int swz_off(int rl, int kq){
  int Pq = (((rl&1)^((rl>>2)&1))<<2) | ((((rl>>1)&1)^((rl>>3)&1))<<1) | (((rl>>2)&1)^((rl>>4)&1));
  return ((rl>>1)<<7) + ((Pq ^ kq)<<4);
}

// ====== k_qkv: QKV projection — 128x256 tile, 8 waves, BK=32, ring-3, 2 blocks/CU ======
// q,k written as FP8 e4m3 (packed u32 per 4 cols); v written bf16 transposed per-batch.
__global__ __launch_bounds__(512, 4) void k_qkv(
    const u16* __restrict__ A, const u16* __restrict__ B,
    uint8_t* __restrict__ q8, uint8_t* __restrict__ k8, u16* __restrict__ vT,
    const float* __restrict__ bias0, const float* __restrict__ bias1, const float* __restrict__ bias2)
{
  __shared__ u16 LDS[36864];   // 72 KiB: B 3x16KB @0, A 3x8KB @49152
  char* Lb = (char*)LDS;
  const int t = threadIdx.x;
  const int l = t & 63, w = t >> 6;
  const int wr = w >> 2, wc = w & 3;
  const int frow = l & 15, kq = l >> 4;
  const int nx = gridDim.x, ny = gridDim.y;
  int f = (int)blockIdx.y*nx + (int)blockIdx.x;
  const int nwg = nx*ny;
  f = (f & 7)*(nwg >> 3) + (f >> 3);
  const int bx = f % nx; const int by = f / nx;
  const int brow = by*128, bcol = bx*256;

  const int pA = t & 7;
  const int LA = t >> 3;
  const int LB0 = t >> 3, LB1 = 64 + (t >> 3);
  const int rlA  = dec_rl(LA, pA),  kqA  = dec_kq(LA, pA);
  const int rlB0 = dec_rl(LB0, pA), kqB0 = dec_kq(LB0, pA);
  const int rlB1 = dec_rl(LB1, pA), kqB1 = dec_kq(LB1, pA);
  const u16* Ap  = A + (size_t)(brow + rlA )*NC + kqA*8;
  const u16* Bp0 = B + (size_t)(bcol + rlB0)*NC + kqB0*8;
  const u16* Bp1 = B + (size_t)(bcol + rlB1)*NC + kqB1*8;

  auto stage = [&](int buf, int kt){
    const size_t ko = (size_t)kt*32;
    gll16(Bp0 + ko, Lb + buf*16384 + t*16);
    gll16(Bp1 + ko, Lb + buf*16384 + 8192 + t*16);
    gll16(Ap  + ko, Lb + 49152 + buf*8192 + t*16);
  };

  int offA[4], offB[4];
  #pragma unroll
  for (int m=0;m<4;m++) offA[m] = swz_off(wr*64 + m*16 + frow, kq);
  #pragma unroll
  for (int c=0;c<4;c++) offB[c] = swz_off(wc*64 + 4*frow + c, kq);

  f32x4 acc[4][4] = {};

  auto body = [&](int buf, int s){
    bf16x8 a4[4], b4[4];
    #pragma unroll
    for (int m=0;m<4;m++) a4[m] = *(const bf16x8*)(Lb + 49152 + buf*8192 + offA[m]);
    #pragma unroll
    for (int c=0;c<4;c++) b4[c] = *(const bf16x8*)(Lb + buf*16384 + offB[c]);
    const bool doStage = (s + 2 < NTQ);
    if (doStage){ int nb = buf+2; if (nb>=3) nb-=3; stage(nb, s+2); }
    asm volatile("s_waitcnt lgkmcnt(0)" ::: "memory");
    __builtin_amdgcn_sched_barrier(0);
    __builtin_amdgcn_s_setprio(1);
    #pragma unroll
    for (int m=0;m<4;m++)
      #pragma unroll
      for (int c=0;c<4;c++)
        acc[m][c] = MFMA_(a4[m], b4[c], acc[m][c]);
    __builtin_amdgcn_s_setprio(0);
    __builtin_amdgcn_sched_barrier(0);
    if (s + 1 < NTQ){
      if (doStage) asm volatile("s_waitcnt vmcnt(3)" ::: "memory");
      else         asm volatile("s_waitcnt vmcnt(0)" ::: "memory");
      __builtin_amdgcn_s_barrier();
    }
  };

  stage(0, 0); stage(1, 1);
  asm volatile("s_waitcnt vmcnt(3)" ::: "memory");
  __builtin_amdgcn_s_barrier();

  #pragma unroll
  for (int i = 0; i < 5; i++){
    body(0, i*3);
    body(1, i*3+1);
    body(2, i*3+2);
  }
  body(0, 15);

  const int col4 = wc*64 + 4*frow;
  const int seg = bcol >> 9;
  const int colr = (bcol & 511) + col4;
  if (seg < 2){
    uint8_t* dq = seg==0 ? q8 : k8;
    const float* bp = seg==0 ? bias0 : bias1;
    const float4 bi = *(const float4*)(bp + colr);
    #pragma unroll
    for (int m=0;m<4;m++){
      #pragma unroll
      for (int r=0;r<4;r++){
        const int rr = brow + wr*64 + m*16 + kq*4 + r;
        unsigned int pv = __builtin_amdgcn_cvt_pk_fp8_f32(acc[m][0][r]+bi.x, acc[m][1][r]+bi.y, 0u, false);
        pv = __builtin_amdgcn_cvt_pk_fp8_f32(acc[m][2][r]+bi.z, acc[m][3][r]+bi.w, pv, true);
        *(unsigned int*)&dq[(size_t)rr*NC + colr] = pv;
      }
    }
  } else {
    const float4 bi = *(const float4*)(bias2 + colr);
    const float bvs[4] = {bi.x, bi.y, bi.z, bi.w};
    #pragma unroll
    for (int m=0;m<4;m++){
      const int rr0 = brow + wr*64 + m*16 + kq*4;
      const int b = rr0 >> 12, sq = rr0 & 4095;
      #pragma unroll
      for (int n=0;n<4;n++){
        u32x2 wv;
        wv[0] = pk2(acc[m][n][0]+bvs[n], acc[m][n][1]+bvs[n]);
        wv[1] = pk2(acc[m][n][2]+bvs[n], acc[m][n][3]+bvs[n]);
        *(u32x2*)&vT[((size_t)(b*NC + colr + n) << 12) + sq] = wv;
      }
    }
  }
}

// ====== k_qk8: FP8 QK^T — 128x256 tile, BK=64(bytes), ring-3, 2 blocks/CU ======
// LDS 72 KiB: A 3x8KB @0, B 3x16KB @24576. fp8 row = 64 B.
// Layout: byte(rl,ks) = (rl>>1)*128 + slot8*8,
//   slot8 = ((rl&1)<<3) | ((((ks>>1) ^ ((rl>>1)&3)) & 3)<<1) | (ks&1)
// A/B reads (stride-1 rows, fixed ks per lane-group): 2-way max (free).
// Staging: unit u (16B) -> rl = 2*(u>>3) + ((u&7)>>2), granule = (u&3... see decode.
__global__ __launch_bounds__(512, 4) void k_qk8(
    const uint8_t* __restrict__ Q8, const uint8_t* __restrict__ K8,
    u16* __restrict__ P, float* __restrict__ partsum, float alpha)
{
  __shared__ char LDS[73728];
  char* LA = LDS;            // 3 x 8192
  char* LB = LDS + 24576;    // 3 x 16384
  const int t = threadIdx.x;
  const int l = t & 63, w = t >> 6;
  const int wr = w >> 2, wc = w & 3;
  const int frow = l & 15, kq = l >> 4;
  // XCD remap (nwg = 2048)
  int f = ((int)blockIdx.z*32 + (int)blockIdx.y)*16 + (int)blockIdx.x;
  f = (f & 7)*256 + (f >> 3);
  const int bx = f & 15; const int t2 = f >> 4;
  const int by = t2 & 31; const int bb = t2 >> 5;
  const int brow = by*128, bcol = bx*256;
  const size_t bOff = (size_t)bb*NSEQ*NC;

  // staging source decode: unit u -> byte offset rl*NC + gr*16
  auto srcoff = [](int u)->int{
    int Lp = u>>3, p2 = u&7;
    int rl = 2*Lp + (p2>>2);
    int gr = (p2&3) ^ (Lp&3);
    return rl*NC + gr*16;
  };
  const uint8_t* Ap  = Q8 + bOff + (size_t)brow*NC + srcoff(t);
  const uint8_t* Bp0 = K8 + bOff + (size_t)bcol*NC + srcoff(t);
  const uint8_t* Bp1 = K8 + bOff + (size_t)bcol*NC + srcoff(t + 512);

  auto stage = [&](int buf, int kt){
    const size_t ko = (size_t)kt*64;
    gll16(Ap  + ko, LA + buf*8192 + t*16);
    gll16(Bp0 + ko, LB + buf*16384 + t*16);
    gll16(Bp1 + ko, LB + buf*16384 + 8192 + t*16);
  };

  auto rdoff = [](int rl, int ks)->int{
    int slot8 = ((rl&1)<<3) | (((((ks>>1) ^ (rl>>1)) & 3))<<1) | (ks&1);
    return ((rl>>1)<<7) + (slot8<<3);
  };
  int offA[4], offB[4];
  #pragma unroll
  for (int m=0;m<4;m++) offA[m] = rdoff(wr*64 + m*16 + frow, kq);
  #pragma unroll
  for (int n=0;n<4;n++) offB[n] = rdoff(wc*64 + n*16 + frow, kq);
  // kh=1 (ks = kq+4): slot8 bit2 flips -> offset ^ 32

  f32x4 acc[4][4] = {};

  auto body = [&](int buf, int s){
    i64 a0[4], a1[4], b0[4], b1[4];
    const char* Ab = LA + buf*8192;
    const char* Bb = LB + buf*16384;
    #pragma unroll
    for (int m=0;m<4;m++){ a0[m] = *(const i64*)(Ab + offA[m]); a1[m] = *(const i64*)(Ab + (offA[m]^32)); }
    #pragma unroll
    for (int n=0;n<4;n++){ b0[n] = *(const i64*)(Bb + offB[n]); b1[n] = *(const i64*)(Bb + (offB[n]^32)); }
    const bool doStage = (s + 2 < 8);
    if (doStage){ int nb = buf+2; if (nb>=3) nb-=3; stage(nb, s+2); }
    asm volatile("s_waitcnt lgkmcnt(0)" ::: "memory");
    __builtin_amdgcn_sched_barrier(0);
    __builtin_amdgcn_s_setprio(1);
    #pragma unroll
    for (int m=0;m<4;m++)
      #pragma unroll
      for (int n=0;n<4;n++){
        acc[m][n] = MFMA8_(a0[m], b0[n], acc[m][n]);
        acc[m][n] = MFMA8_(a1[m], b1[n], acc[m][n]);
      }
    __builtin_amdgcn_s_setprio(0);
    __builtin_amdgcn_sched_barrier(0);
    if (s + 1 < 8){
      if (doStage) asm volatile("s_waitcnt vmcnt(3)" ::: "memory");
      else         asm volatile("s_waitcnt vmcnt(0)" ::: "memory");
      __builtin_amdgcn_s_barrier();
    }
  };

  stage(0, 0); stage(1, 1);
  asm volatile("s_waitcnt vmcnt(3)" ::: "memory");
  __builtin_amdgcn_s_barrier();

  body(0,0); body(1,1); body(2,2); body(0,3);
  body(1,4); body(2,5); body(0,6); body(1,7);

  // epilogue: exp + bf16 P store (scalar; QK^T is store-insensitive) + row partials
  u16* Pp = P + (size_t)bb*NSEQ*NSEQ;
  #pragma unroll
  for (int m=0;m<4;m++){
    #pragma unroll
    for (int r=0;r<4;r++){
      const int rr = brow + wr*64 + m*16 + kq*4 + r;
      float rs = 0.f;
      #pragma unroll
      for (int n=0;n<4;n++){
        u16 pv = f2bf(__expf(alpha*acc[m][n][r]));
        Pp[(size_t)rr*NSEQ + bcol + wc*64 + n*16 + frow] = pv;
        rs += bfu(pv);
      }
      rs += __shfl_xor(rs, 1); rs += __shfl_xor(rs, 2);
      rs += __shfl_xor(rs, 4); rs += __shfl_xor(rs, 8);
      if (frow == 0)
        partsum[((size_t)bb*NSEQ + rr)*64 + bx*4 + wc] = rs;
    }
  }
}

// ====== k_t256o: out-projection — 128x128 tile, 4 waves, BK=32, ring-3, 48KB ======
__global__ __launch_bounds__(256, 3) void k_t256o(
    const u16* __restrict__ A, const u16* __restrict__ B,
    float* __restrict__ out, const float* __restrict__ bias, const float* __restrict__ res)
{
  __shared__ u16 LDS[24576];
  char* Lb = (char*)LDS;
  const int t = threadIdx.x;
  const int l = t & 63, w = t >> 6;
  const int wr = w >> 1, wc = w & 1;
  const int frow = l & 15, kq = l >> 4;
  int f = (int)blockIdx.y*4 + (int)blockIdx.x;
  f = (f & 7)*64 + (f >> 3);
  const int bx = f & 3; const int by = f >> 2;
  const int brow = by*128, bcol = bx*128;

  const int pA = t & 7;
  const int L0 = t >> 3;
  const int rl0 = dec_rl(L0, pA),      kq0 = dec_kq(L0, pA);
  const int rl1 = dec_rl(L0+32, pA),   kq1 = dec_kq(L0+32, pA);
  const u16* Ap0 = A + (size_t)(brow + rl0)*NC + kq0*8;
  const u16* Ap1 = A + (size_t)(brow + rl1)*NC + kq1*8;
  const u16* Bp0 = B + (size_t)(bcol + rl0)*NC + kq0*8;
  const u16* Bp1 = B + (size_t)(bcol + rl1)*NC + kq1*8;

  auto stage = [&](int buf, int kt){
    const size_t ko = (size_t)kt*32;
    gll16(Ap0 + ko, Lb + buf*16384 + t*16);
    gll16(Ap1 + ko, Lb + buf*16384 + 4096 + t*16);
    gll16(Bp0 + ko, Lb + buf*16384 + 8192 + t*16);
    gll16(Bp1 + ko, Lb + buf*16384 + 12288 + t*16);
  };

  int offA[4], offB[4];
  #pragma unroll
  for (int m=0;m<4;m++) offA[m] = swz_off(wr*64 + m*16 + frow, kq);
  #pragma unroll
  for (int c=0;c<4;c++) offB[c] = swz_off(wc*64 + 4*frow + c, kq);

  f32x4 acc[4][4] = {};

  auto body = [&](int buf, int s){
    bf16x8 a4[4], b4[4];
    #pragma unroll
    for (int m=0;m<4;m++) a4[m] = *(const bf16x8*)(Lb + buf*16384 + offA[m]);
    #pragma unroll
    for (int c=0;c<4;c++) b4[c] = *(const bf16x8*)(Lb + buf*16384 + 8192 + offB[c]);
    const bool doStage = (s + 2 < NTQ);
    if (doStage){ int nb = buf+2; if (nb>=3) nb-=3; stage(nb, s+2); }
    asm volatile("s_waitcnt lgkmcnt(0)" ::: "memory");
    __builtin_amdgcn_sched_barrier(0);
    __builtin_amdgcn_s_setprio(1);
    #pragma unroll
    for (int m=0;m<4;m++)
      #pragma unroll
      for (int c=0;c<4;c++)
        acc[m][c] = MFMA_(a4[m], b4[c], acc[m][c]);
    __builtin_amdgcn_s_setprio(0);
    __builtin_amdgcn_sched_barrier(0);
    if (s + 1 < NTQ){
      if (doStage) asm volatile("s_waitcnt vmcnt(4)" ::: "memory");
      else         asm volatile("s_waitcnt vmcnt(0)" ::: "memory");
      __builtin_amdgcn_s_barrier();
    }
  };

  stage(0, 0); stage(1, 1);
  asm volatile("s_waitcnt vmcnt(4)" ::: "memory");
  __builtin_amdgcn_s_barrier();

  #pragma unroll
  for (int i = 0; i < 5; i++){
    body(0, i*3);
    body(1, i*3+1);
    body(2, i*3+2);
  }
  body(0, 15);

  const int c = bcol + wc*64 + 4*frow;
  const float4 bi = *(const float4*)(bias + c);
  #pragma unroll
  for (int m=0;m<4;m++){
    #pragma unroll
    for (int r=0;r<4;r++){
      const int rr = brow + wr*64 + m*16 + kq*4 + r;
      const float4 rv = *(const float4*)(res + (size_t)rr*NC + c);
      float4 ov;
      ov.x = acc[m][0][r] + bi.x + rv.x;
      ov.y = acc[m][1][r] + bi.y + rv.y;
      ov.z = acc[m][2][r] + bi.z + rv.z;
      ov.w = acc[m][3][r] + bi.w + rv.w;
      *(float4*)&out[(size_t)rr*NC + c] = ov;
    }
  }
}

extern "C" void kernel_launch(void* const* d_in, const int* in_sizes, int n_in,
                              void* d_out, int out_size, void* d_ws, size_t ws_size,
                              hipStream_t stream){
  const float* x   = (const float*)d_in[0];
  const float* gsc = (const float*)d_in[1];
  const float* gbi = (const float*)d_in[2];
  const float* wq  = (const float*)d_in[3];
  const float* bq  = (const float*)d_in[4];
  const float* wk  = (const float*)d_in[5];
  const float* bk  = (const float*)d_in[6];
  const float* wv  = (const float*)d_in[7];
  const float* bv  = (const float*)d_in[8];
  const float* wo  = (const float*)d_in[9];
  const float* bo  = (const float*)d_in[10];
  float* out = (float*)d_out;

  char* wsp = (char*)d_ws;
  size_t off = 0;
  auto alloc = [&](size_t bytes)->void*{ void* p = wsp + off; off += (bytes + 255) & ~(size_t)255; return p; };
  float* stats   = (float*)alloc((size_t)NB*NG*2*sizeof(float));
  float* sums    = (float*)alloc((size_t)NM*sizeof(float));
  float* partsum = (float*)alloc((size_t)NM*64*sizeof(float));
  u16* xbf   = (u16*)alloc((size_t)NM*NC*2);   // bf16 copy of x (dead after gn_apply2)
  u16* hn    = (u16*)alloc((size_t)NM*NC*2);   // adjacent to xbf (dead after QKV)
  u16* wqkvT = (u16*)alloc((size_t)3*NC*NC*2);
  u16* woT   = (u16*)alloc((size_t)NC*NC*2);
  uint8_t* q8 = (uint8_t*)alloc((size_t)NM*NC);
  uint8_t* k8 = (uint8_t*)alloc((size_t)NM*NC);
  u16* vT    = (u16*)alloc((size_t)NM*NC*2);
  u16* o     = (u16*)alloc((size_t)NM*NC*2);
  u16* P     = (u16*)alloc((size_t)NB*NSEQ*NSEQ*2);
  u16* opart = xbf;  // PV split-K partials [2][NM][NC] alias xbf+hn (32 MiB, both dead)

  k_zero<<<1,256,0,stream>>>(stats, NB*NG*2);
  k_gn_stats2<<<NB*64,256,0,stream>>>(x, xbf, stats);
  k_gn_apply2<<<4096,256,0,stream>>>(xbf, stats, gsc, gbi, hn);
  k_wtrans4<<<4096,256,0,stream>>>(wq, wk, wv, wo, wqkvT, woT);

  // QKV projection: M=16384, N=1536, K=512; q,k out in fp8
  k_qkv<<<dim3(6,128,1),512,0,stream>>>(hn, wqkvT, q8, k8, vT, bq, bk, bv);

  const float scale = 0.044194173824159216f;  // 512^-0.5
  // QK^T in fp8: M=N=4096, K=512, z=4
  k_qk8<<<dim3(16,32,NB),512,0,stream>>>(q8, k8, P, partsum, scale);
  k_sumred<<<NM/4,256,0,stream>>>(partsum, sums);
  // PV split-K=2: 8-phase 256x256 bf16 (unchanged)
  k_gemm8pv<<<dim3(2,16,8),512,0,stream>>>(P, vT,
      (size_t)NSEQ*NSEQ, (size_t)NC*NSEQ, NSEQ, NSEQ, NSEQ/2, opart);
  k_pvred<<<NM*NC/8/256,256,0,stream>>>(opart, sums, o);
  // output projection + bias + residual
  k_t256o<<<dim3(4,128,1),256,0,stream>>>(o, woT, out, bo, x);
}

// Round 11
// 204.660 us; speedup vs baseline: 8.3438x; 1.1198x over previous
//
#include <hip/hip_runtime.h>
#include <stdint.h>

typedef unsigned short u16;
typedef long i64;
typedef __bf16 bf16x8 __attribute__((ext_vector_type(8)));
typedef float f32x4 __attribute__((ext_vector_type(4)));
typedef uint32_t u32x2 __attribute__((ext_vector_type(2)));
typedef uint32_t u32x4 __attribute__((ext_vector_type(4)));

#define NB 4
#define NC 512
#define NG 32
#define NSEQ 4096
#define NM (NB*NSEQ)

#define MFMA_(a,b,c) __builtin_amdgcn_mfma_f32_16x16x32_bf16(a,b,c,0,0,0)
#define MFMA8_(a,b,c) __builtin_amdgcn_mfma_f32_16x16x32_fp8_fp8(a,b,c,0,0,0)

__device__ __forceinline__ u16 f2bf(float f){
  uint32_t u = __builtin_bit_cast(uint32_t, f);
  u += 0x7FFFu + ((u >> 16) & 1u);
  return (u16)(u >> 16);
}
__device__ __forceinline__ float bfu(uint32_t lo16){
  return __builtin_bit_cast(float, lo16 << 16);
}
__device__ __forceinline__ uint32_t pk2(float a, float b){
  return (uint32_t)f2bf(a) | ((uint32_t)f2bf(b) << 16);
}

__device__ __forceinline__ void gll16(const void* g, void* l){
  __builtin_amdgcn_global_load_lds(
      (const __attribute__((address_space(1))) void*)g,
      (__attribute__((address_space(3))) void*)l, 16, 0, 0);
}

__global__ void k_zero(float* p, int n){
  int i = blockIdx.x*blockDim.x + threadIdx.x;
  if (i < n) p[i] = 0.f;
}

// GN pass 1: row-major read of x, per-group partial sums + bf16 copy of x.
__global__ __launch_bounds__(256) void k_gn_stats2(const float* __restrict__ x,
    u16* __restrict__ xbf, float* __restrict__ stats){
  int blk = blockIdx.x;
  int b = blk >> 6, ch = blk & 63;
  int t = threadIdx.x;
  int colv = t & 127;
  int r0 = ch*64 + (t >> 7);
  const float* xp = x  + (size_t)b*NSEQ*NC + (size_t)r0*NC + colv*4;
  u16* xb       = xbf + (size_t)b*NSEQ*NC + (size_t)r0*NC + colv*4;
  float s1 = 0.f, s2 = 0.f;
  #pragma unroll 4
  for (int i = 0; i < 32; i++){
    float4 v = *(const float4*)(xp + (size_t)i*2*NC);
    s1 += v.x+v.y+v.z+v.w;
    s2 += v.x*v.x+v.y*v.y+v.z*v.z+v.w*v.w;
    ushort4 o; o.x=f2bf(v.x); o.y=f2bf(v.y); o.z=f2bf(v.z); o.w=f2bf(v.w);
    *(ushort4*)(xb + (size_t)i*2*NC) = o;
  }
  s1 += __shfl_xor(s1,1); s2 += __shfl_xor(s2,1);
  s1 += __shfl_xor(s1,2); s2 += __shfl_xor(s2,2);
  __shared__ float ls1[4][16], ls2[4][16];
  int w = t >> 6, l = t & 63;
  if ((l & 3) == 0){ ls1[w][l>>2] = s1; ls2[w][l>>2] = s2; }
  __syncthreads();
  if (t < 32){
    int g = t;
    int wlo = g >> 4;
    float a1 = ls1[wlo][g&15] + ls1[wlo+2][g&15];
    float a2 = ls2[wlo][g&15] + ls2[wlo+2][g&15];
    atomicAdd(&stats[(b*NG+g)*2+0], a1);
    atomicAdd(&stats[(b*NG+g)*2+1], a2);
  }
}

// GN pass 2: read bf16 x-copy, normalize+affine, write hn.
__global__ __launch_bounds__(256) void k_gn_apply2(const u16* __restrict__ xbf,
    const float* __restrict__ stats, const float* __restrict__ gsc,
    const float* __restrict__ gbi, u16* __restrict__ hn){
  const float inv_cnt = 1.f/((float)NSEQ*16.f);
  size_t i = ((size_t)blockIdx.x*256 + threadIdx.x)*8;
  int c = (int)(i & 511);
  int b = (int)(i >> 21);
  int g = c >> 4;
  float s1 = stats[(b*NG+g)*2], s2 = stats[(b*NG+g)*2+1];
  float mean = s1*inv_cnt;
  float rstd = rsqrtf(s2*inv_cnt - mean*mean + 1e-6f);
  u32x4 v = *(const u32x4*)(xbf + i);
  float4 scA = *(const float4*)(gsc + c), scB = *(const float4*)(gsc + c + 4);
  float4 biA = *(const float4*)(gbi + c), biB = *(const float4*)(gbi + c + 4);
  const float sc[8] = {scA.x,scA.y,scA.z,scA.w,scB.x,scB.y,scB.z,scB.w};
  const float bi[8] = {biA.x,biA.y,biA.z,biA.w,biB.x,biB.y,biB.z,biB.w};
  u32x4 o;
  #pragma unroll
  for (int j = 0; j < 4; j++){
    float lo = bfu(v[j] & 0xFFFFu);
    float hi = __builtin_bit_cast(float, v[j] & 0xFFFF0000u);
    o[j] = pk2((lo-mean)*rstd*sc[2*j] + bi[2*j], (hi-mean)*rstd*sc[2*j+1] + bi[2*j+1]);
  }
  *(u32x4*)(hn + i) = o;
}

__global__ __launch_bounds__(256) void k_wtrans4(const float* __restrict__ wq, const float* __restrict__ wk,
    const float* __restrict__ wv, const float* __restrict__ wo,
    u16* __restrict__ wqkvT, u16* __restrict__ woT){
  int j = blockIdx.x*256 + threadIdx.x;
  int wsel = j >> 18, r = j & 262143;
  int n = r >> 9, k = r & 511;
  const float* src = wsel==0?wq : wsel==1?wk : wsel==2?wv : wo;
  u16 v = f2bf(src[k*512 + n]);
  if (wsel < 3) wqkvT[(size_t)wsel*262144 + r] = v;
  else          woT[r] = v;
}

__global__ __launch_bounds__(256) void k_sumred(const float* __restrict__ part, float* __restrict__ sums){
  int row = blockIdx.x*4 + (threadIdx.x >> 6);
  int l = threadIdx.x & 63;
  float s = part[(size_t)row*64 + l];
  #pragma unroll
  for (int o = 32; o; o >>= 1) s += __shfl_xor(s, o);
  if (l == 0) sums[row] = s;
}

__global__ __launch_bounds__(256) void k_pvred(const u16* __restrict__ op, const float* __restrict__ sums,
    u16* __restrict__ o){
  size_t i = ((size_t)blockIdx.x*256 + threadIdx.x)*8;
  int row = (int)(i >> 9);
  float inv = 1.f/sums[row];
  u32x4 a = __builtin_nontemporal_load((const u32x4*)(op + i));
  u32x4 b = __builtin_nontemporal_load((const u32x4*)(op + (size_t)NM*NC + i));
  uint32_t r[4];
  #pragma unroll
  for (int j=0;j<4;j++){
    float lo = (bfu(a[j] & 0xFFFFu) + bfu(b[j] & 0xFFFFu)) * inv;
    float hi = (__builtin_bit_cast(float, a[j] & 0xFFFF0000u) +
                __builtin_bit_cast(float, b[j] & 0xFFFF0000u)) * inv;
    r[j] = (uint32_t)f2bf(lo) | ((uint32_t)f2bf(hi) << 16);
  }
  *(uint4*)(o + i) = make_uint4(r[0], r[1], r[2], r[3]);
}

// ============ bf16 16B-granule swizzle machinery (QKV / out-proj) ============
#define NTQ 16   // K=512 / BK=32 (bf16 kernels)

__device__ __forceinline__ int dec_rl(int L, int p){ return 2*L + ((p>>2) ^ ((L>>1)&1)); }
__device__ __forceinline__ int dec_kq(int L, int p){
  int P01 = ((((L)&1)^((L>>2)&1))<<1) | (((L>>1)&1)^((L>>3)&1));
  return (p&3) ^ P01;
}
__device__ __forceinline__ int swz_off(int rl, int kq){
  int Pq = (((rl&1)^((rl>>2)&1))<<2) | ((((rl>>1)&1)^((rl>>3)&1))<<1) | (((rl>>2)&1)^((rl>>4)&1));
  return ((rl>>1)<<7) + ((Pq ^ kq)<<4);
}

// ====== k_qkv: QKV projection — 128x256 tile, 8 waves, BK=32, ring-3, 2 blocks/CU ======
// q,k,v ALL written as FP8 e4m3; v transposed per-batch ([b][c][seq], 1B elems).
__global__ __launch_bounds__(512, 4) void k_qkv(
    const u16* __restrict__ A, const u16* __restrict__ B,
    uint8_t* __restrict__ q8, uint8_t* __restrict__ k8, uint8_t* __restrict__ v8T,
    const float* __restrict__ bias0, const float* __restrict__ bias1, const float* __restrict__ bias2)
{
  __shared__ u16 LDS[36864];   // 72 KiB: B 3x16KB @0, A 3x8KB @49152
  char* Lb = (char*)LDS;
  const int t = threadIdx.x;
  const int l = t & 63, w = t >> 6;
  const int wr = w >> 2, wc = w & 3;
  const int frow = l & 15, kq = l >> 4;
  const int nx = gridDim.x, ny = gridDim.y;
  int f = (int)blockIdx.y*nx + (int)blockIdx.x;
  const int nwg = nx*ny;
  f = (f & 7)*(nwg >> 3) + (f >> 3);
  const int bx = f % nx; const int by = f / nx;
  const int brow = by*128, bcol = bx*256;

  const int pA = t & 7;
  const int LA = t >> 3;
  const int LB0 = t >> 3, LB1 = 64 + (t >> 3);
  const int rlA  = dec_rl(LA, pA),  kqA  = dec_kq(LA, pA);
  const int rlB0 = dec_rl(LB0, pA), kqB0 = dec_kq(LB0, pA);
  const int rlB1 = dec_rl(LB1, pA), kqB1 = dec_kq(LB1, pA);
  const u16* Ap  = A + (size_t)(brow + rlA )*NC + kqA*8;
  const u16* Bp0 = B + (size_t)(bcol + rlB0)*NC + kqB0*8;
  const u16* Bp1 = B + (size_t)(bcol + rlB1)*NC + kqB1*8;

  auto stage = [&](int buf, int kt){
    const size_t ko = (size_t)kt*32;
    gll16(Bp0 + ko, Lb + buf*16384 + t*16);
    gll16(Bp1 + ko, Lb + buf*16384 + 8192 + t*16);
    gll16(Ap  + ko, Lb + 49152 + buf*8192 + t*16);
  };

  int offA[4], offB[4];
  #pragma unroll
  for (int m=0;m<4;m++) offA[m] = swz_off(wr*64 + m*16 + frow, kq);
  #pragma unroll
  for (int c=0;c<4;c++) offB[c] = swz_off(wc*64 + 4*frow + c, kq);

  f32x4 acc[4][4] = {};

  auto body = [&](int buf, int s){
    bf16x8 a4[4], b4[4];
    #pragma unroll
    for (int m=0;m<4;m++) a4[m] = *(const bf16x8*)(Lb + 49152 + buf*8192 + offA[m]);
    #pragma unroll
    for (int c=0;c<4;c++) b4[c] = *(const bf16x8*)(Lb + buf*16384 + offB[c]);
    const bool doStage = (s + 2 < NTQ);
    if (doStage){ int nb = buf+2; if (nb>=3) nb-=3; stage(nb, s+2); }
    asm volatile("s_waitcnt lgkmcnt(0)" ::: "memory");
    __builtin_amdgcn_sched_barrier(0);
    __builtin_amdgcn_s_setprio(1);
    #pragma unroll
    for (int m=0;m<4;m++)
      #pragma unroll
      for (int c=0;c<4;c++)
        acc[m][c] = MFMA_(a4[m], b4[c], acc[m][c]);
    __builtin_amdgcn_s_setprio(0);
    __builtin_amdgcn_sched_barrier(0);
    if (s + 1 < NTQ){
      if (doStage) asm volatile("s_waitcnt vmcnt(3)" ::: "memory");
      else         asm volatile("s_waitcnt vmcnt(0)" ::: "memory");
      __builtin_amdgcn_s_barrier();
    }
  };

  stage(0, 0); stage(1, 1);
  asm volatile("s_waitcnt vmcnt(3)" ::: "memory");
  __builtin_amdgcn_s_barrier();

  #pragma unroll
  for (int i = 0; i < 5; i++){
    body(0, i*3);
    body(1, i*3+1);
    body(2, i*3+2);
  }
  body(0, 15);

  const int col4 = wc*64 + 4*frow;
  const int seg = bcol >> 9;
  const int colr = (bcol & 511) + col4;
  if (seg < 2){
    uint8_t* dq = seg==0 ? q8 : k8;
    const float* bp = seg==0 ? bias0 : bias1;
    const float4 bi = *(const float4*)(bp + colr);
    #pragma unroll
    for (int m=0;m<4;m++){
      #pragma unroll
      for (int r=0;r<4;r++){
        const int rr = brow + wr*64 + m*16 + kq*4 + r;
        unsigned int pv = __builtin_amdgcn_cvt_pk_fp8_f32(acc[m][0][r]+bi.x, acc[m][1][r]+bi.y, 0u, false);
        pv = __builtin_amdgcn_cvt_pk_fp8_f32(acc[m][2][r]+bi.z, acc[m][3][r]+bi.w, pv, true);
        *(unsigned int*)&dq[(size_t)rr*NC + colr] = pv;
      }
    }
  } else {
    const float4 bi = *(const float4*)(bias2 + colr);
    const float bvs[4] = {bi.x, bi.y, bi.z, bi.w};
    #pragma unroll
    for (int m=0;m<4;m++){
      const int rr0 = brow + wr*64 + m*16 + kq*4;
      const int b = rr0 >> 12, sq = rr0 & 4095;
      #pragma unroll
      for (int n=0;n<4;n++){
        unsigned int pv = __builtin_amdgcn_cvt_pk_fp8_f32(acc[m][n][0]+bvs[n], acc[m][n][1]+bvs[n], 0u, false);
        pv = __builtin_amdgcn_cvt_pk_fp8_f32(acc[m][n][2]+bvs[n], acc[m][n][3]+bvs[n], pv, true);
        *(unsigned int*)&v8T[((size_t)(b*NC + colr + n) << 12) + sq] = pv;
      }
    }
  }
}

// ====== shared fp8 LDS machinery (qk8 / pv8): 64B rows, 128B lines ======
// phys slot8(rl,ks) verified round 8 (stride-1 reads, 2-way free);
// cmap permutes LOGICAL row -> phys row at the gll16 SOURCE so that
// lane frow's 4 n-values are logical rows 4*frow+n (packed stores),
// while read addressing + LDS layout stay byte-identical to round 8.
__device__ __forceinline__ int rdoff8(int rl, int ks){
  int slot8 = ((rl&1)<<3) | (((((ks>>1) ^ (rl>>1)) & 3))<<1) | (ks&1);
  return ((rl>>1)<<7) + (slot8<<3);
}
__device__ __forceinline__ int cmap64(int p){  // bijection within 64-row groups
  return (p & 192) + (((p & 15) << 2) | ((p >> 4) & 3));
}

// ====== k_qk8: FP8 QK^T — 128x256 tile, BK=64B, ring-3, 2 blocks/CU ======
// Output P in fp8 e4m3, packed u32 stores; f32 row-partials.
__global__ __launch_bounds__(512, 4) void k_qk8(
    const uint8_t* __restrict__ Q8, const uint8_t* __restrict__ K8,
    uint8_t* __restrict__ P8, float* __restrict__ partsum, float alpha)
{
  __shared__ char LDS[73728];
  char* LA = LDS;            // 3 x 8192
  char* LB = LDS + 24576;    // 3 x 16384
  const int t = threadIdx.x;
  const int l = t & 63, w = t >> 6;
  const int wr = w >> 2, wc = w & 3;
  const int frow = l & 15, kq = l >> 4;
  int f = ((int)blockIdx.z*32 + (int)blockIdx.y)*16 + (int)blockIdx.x;
  f = (f & 7)*256 + (f >> 3);
  const int bx = f & 15; const int t2 = f >> 4;
  const int by = t2 & 31; const int bb = t2 >> 5;
  const int brow = by*128, bcol = bx*256;
  const size_t bOff = (size_t)bb*NSEQ*NC;

  const int Lp = t >> 3, p2 = t & 7;
  const int rlu = 2*Lp + (p2 >> 2);
  const int gru = (p2 & 3) ^ (Lp & 3);
  const uint8_t* Ap  = Q8 + bOff + (size_t)(brow + rlu)*NC + gru*16;
  const uint8_t* Bp0 = K8 + bOff + (size_t)(bcol + cmap64(rlu))*NC + gru*16;
  const uint8_t* Bp1 = K8 + bOff + (size_t)(bcol + cmap64(rlu + 128))*NC + gru*16;

  auto stage = [&](int buf, int kt){
    const size_t ko = (size_t)kt*64;
    gll16(Ap  + ko, LA + buf*8192 + t*16);
    gll16(Bp0 + ko, LB + buf*16384 + t*16);
    gll16(Bp1 + ko, LB + buf*16384 + 8192 + t*16);
  };

  int offA[4], offB[4];
  #pragma unroll
  for (int m=0;m<4;m++) offA[m] = rdoff8(wr*64 + m*16 + frow, kq);
  #pragma unroll
  for (int n=0;n<4;n++) offB[n] = rdoff8(wc*64 + n*16 + frow, kq);

  f32x4 acc[4][4] = {};

  auto body = [&](int buf, int s){
    i64 a0[4], a1[4], b0[4], b1[4];
    const char* Ab = LA + buf*8192;
    const char* Bb = LB + buf*16384;
    #pragma unroll
    for (int m=0;m<4;m++){ a0[m] = *(const i64*)(Ab + offA[m]); a1[m] = *(const i64*)(Ab + (offA[m]^32)); }
    #pragma unroll
    for (int n=0;n<4;n++){ b0[n] = *(const i64*)(Bb + offB[n]); b1[n] = *(const i64*)(Bb + (offB[n]^32)); }
    const bool doStage = (s + 2 < 8);
    if (doStage){ int nb = buf+2; if (nb>=3) nb-=3; stage(nb, s+2); }
    asm volatile("s_waitcnt lgkmcnt(0)" ::: "memory");
    __builtin_amdgcn_sched_barrier(0);
    __builtin_amdgcn_s_setprio(1);
    #pragma unroll
    for (int m=0;m<4;m++)
      #pragma unroll
      for (int n=0;n<4;n++){
        acc[m][n] = MFMA8_(a0[m], b0[n], acc[m][n]);
        acc[m][n] = MFMA8_(a1[m], b1[n], acc[m][n]);
      }
    __builtin_amdgcn_s_setprio(0);
    __builtin_amdgcn_sched_barrier(0);
    if (s + 1 < 8){
      if (doStage) asm volatile("s_waitcnt vmcnt(3)" ::: "memory");
      else         asm volatile("s_waitcnt vmcnt(0)" ::: "memory");
      __builtin_amdgcn_s_barrier();
    }
  };

  stage(0, 0); stage(1, 1);
  asm volatile("s_waitcnt vmcnt(3)" ::: "memory");
  __builtin_amdgcn_s_barrier();

  body(0,0); body(1,1); body(2,2); body(0,3);
  body(1,4); body(2,5); body(0,6); body(1,7);

  // epilogue: exp -> fp8 P (packed u32, cols 4*frow..+3) + f32 row partials
  uint8_t* Pp = P8 + (size_t)bb*NSEQ*NSEQ;
  const int colp = bcol + wc*64 + 4*frow;
  #pragma unroll
  for (int m=0;m<4;m++){
    #pragma unroll
    for (int r=0;r<4;r++){
      const int rr = brow + wr*64 + m*16 + kq*4 + r;
      float e0 = __expf(alpha*acc[m][0][r]);
      float e1 = __expf(alpha*acc[m][1][r]);
      float e2 = __expf(alpha*acc[m][2][r]);
      float e3 = __expf(alpha*acc[m][3][r]);
      unsigned int p4 = __builtin_amdgcn_cvt_pk_fp8_f32(e0, e1, 0u, false);
      p4 = __builtin_amdgcn_cvt_pk_fp8_f32(e2, e3, p4, true);
      __builtin_nontemporal_store(p4, (unsigned int*)&Pp[(size_t)rr*NSEQ + colp]);
      float rs = e0 + e1 + e2 + e3;
      rs += __shfl_xor(rs, 1); rs += __shfl_xor(rs, 2);
      rs += __shfl_xor(rs, 4); rs += __shfl_xor(rs, 8);
      if (frow == 0)
        partsum[((size_t)bb*NSEQ + rr)*64 + bx*4 + wc] = rs;
    }
  }
}

// ====== k_pv8: FP8 PV split-K — qk8-clone geometry, NT=32, 2 blocks/CU ======
// A = P8 [b][4096 q][4096 keys], B = v8T [b][512 c][4096 seq]; z=(split,b).
// B-rows (channels) source-permuted via cmap64 -> packed bf16-partial stores.
__global__ __launch_bounds__(512, 4) void k_pv8(
    const uint8_t* __restrict__ P8, const uint8_t* __restrict__ V8,
    u16* __restrict__ opart)
{
  __shared__ char LDS[73728];
  char* LA = LDS;            // 3 x 8192  (128 q-rows x 64B)
  char* LB = LDS + 24576;    // 3 x 16384 (256 c-rows x 64B)
  const int t = threadIdx.x;
  const int l = t & 63, w = t >> 6;
  const int wr = w >> 2, wc = w & 3;
  const int frow = l & 15, kq = l >> 4;
  // grid (2,32,8) -> nwg=512
  int f = ((int)blockIdx.z*32 + (int)blockIdx.y)*2 + (int)blockIdx.x;
  f = (f & 7)*64 + (f >> 3);
  const int bx = f & 1; const int t2 = f >> 1;
  const int by = t2 & 31; const int bz = t2 >> 5;
  const int bb = bz & 3; const int sp = bz >> 2;
  const int brow = by*128, bcol = bx*256;
  const int kOff = sp*(NSEQ/2);    // byte offset into 4096-B rows

  const int Lp = t >> 3, p2 = t & 7;
  const int rlu = 2*Lp + (p2 >> 2);
  const int gru = (p2 & 3) ^ (Lp & 3);
  const uint8_t* Ap  = P8 + (size_t)bb*NSEQ*NSEQ + (size_t)(brow + rlu)*NSEQ + kOff + gru*16;
  const uint8_t* Bp0 = V8 + (size_t)bb*NC*NSEQ + (size_t)(bcol + cmap64(rlu))*NSEQ + kOff + gru*16;
  const uint8_t* Bp1 = V8 + (size_t)bb*NC*NSEQ + (size_t)(bcol + cmap64(rlu + 128))*NSEQ + kOff + gru*16;

  auto stage = [&](int buf, int kt){
    const size_t ko = (size_t)kt*64;
    gll16(Ap  + ko, LA + buf*8192 + t*16);
    gll16(Bp0 + ko, LB + buf*16384 + t*16);
    gll16(Bp1 + ko, LB + buf*16384 + 8192 + t*16);
  };

  int offA[4], offB[4];
  #pragma unroll
  for (int m=0;m<4;m++) offA[m] = rdoff8(wr*64 + m*16 + frow, kq);
  #pragma unroll
  for (int n=0;n<4;n++) offB[n] = rdoff8(wc*64 + n*16 + frow, kq);

  f32x4 acc[4][4] = {};

  auto body = [&](int buf, int s){
    i64 a0[4], a1[4], b0[4], b1[4];
    const char* Ab = LA + buf*8192;
    const char* Bb = LB + buf*16384;
    #pragma unroll
    for (int m=0;m<4;m++){ a0[m] = *(const i64*)(Ab + offA[m]); a1[m] = *(const i64*)(Ab + (offA[m]^32)); }
    #pragma unroll
    for (int n=0;n<4;n++){ b0[n] = *(const i64*)(Bb + offB[n]); b1[n] = *(const i64*)(Bb + (offB[n]^32)); }
    const bool doStage = (s + 2 < 32);
    if (doStage){ int nb = buf+2; if (nb>=3) nb-=3; stage(nb, s+2); }
    asm volatile("s_waitcnt lgkmcnt(0)" ::: "memory");
    __builtin_amdgcn_sched_barrier(0);
    __builtin_amdgcn_s_setprio(1);
    #pragma unroll
    for (int m=0;m<4;m++)
      #pragma unroll
      for (int n=0;n<4;n++){
        acc[m][n] = MFMA8_(a0[m], b0[n], acc[m][n]);
        acc[m][n] = MFMA8_(a1[m], b1[n], acc[m][n]);
      }
    __builtin_amdgcn_s_setprio(0);
    __builtin_amdgcn_sched_barrier(0);
    if (s + 1 < 32){
      if (doStage) asm volatile("s_waitcnt vmcnt(3)" ::: "memory");
      else         asm volatile("s_waitcnt vmcnt(0)" ::: "memory");
      __builtin_amdgcn_s_barrier();
    }
  };

  stage(0, 0); stage(1, 1);
  asm volatile("s_waitcnt vmcnt(3)" ::: "memory");
  __builtin_amdgcn_s_barrier();

  #pragma unroll
  for (int i = 0; i < 10; i++){
    body(0, i*3);
    body(1, i*3+1);
    body(2, i*3+2);
  }
  body(0, 30); body(1, 31);

  // epilogue: bf16 partials, packed 8B stores (channels 4*frow..+3)
  u16* op = opart + (size_t)sp*NM*NC + (size_t)bb*NSEQ*NC;
  const int col4 = bcol + wc*64 + 4*frow;
  #pragma unroll
  for (int m=0;m<4;m++){
    #pragma unroll
    for (int r=0;r<4;r++){
      const int rr = brow + wr*64 + m*16 + kq*4 + r;
      u32x2 wv;
      wv[0] = pk2(acc[m][0][r], acc[m][1][r]);
      wv[1] = pk2(acc[m][2][r], acc[m][3][r]);
      __builtin_nontemporal_store(wv, (u32x2*)&op[(size_t)rr*NC + col4]);
    }
  }
}

// ====== k_t256o: out-projection — 128x128 tile, 4 waves, BK=32, ring-3, 48KB ======
__global__ __launch_bounds__(256, 3) void k_t256o(
    const u16* __restrict__ A, const u16* __restrict__ B,
    float* __restrict__ out, const float* __restrict__ bias, const float* __restrict__ res)
{
  __shared__ u16 LDS[24576];
  char* Lb = (char*)LDS;
  const int t = threadIdx.x;
  const int l = t & 63, w = t >> 6;
  const int wr = w >> 1, wc = w & 1;
  const int frow = l & 15, kq = l >> 4;
  int f = (int)blockIdx.y*4 + (int)blockIdx.x;
  f = (f & 7)*64 + (f >> 3);
  const int bx = f & 3; const int by = f >> 2;
  const int brow = by*128, bcol = bx*128;

  const int pA = t & 7;
  const int L0 = t >> 3;
  const int rl0 = dec_rl(L0, pA),      kq0 = dec_kq(L0, pA);
  const int rl1 = dec_rl(L0+32, pA),   kq1 = dec_kq(L0+32, pA);
  const u16* Ap0 = A + (size_t)(brow + rl0)*NC + kq0*8;
  const u16* Ap1 = A + (size_t)(brow + rl1)*NC + kq1*8;
  const u16* Bp0 = B + (size_t)(bcol + rl0)*NC + kq0*8;
  const u16* Bp1 = B + (size_t)(bcol + rl1)*NC + kq1*8;

  auto stage = [&](int buf, int kt){
    const size_t ko = (size_t)kt*32;
    gll16(Ap0 + ko, Lb + buf*16384 + t*16);
    gll16(Ap1 + ko, Lb + buf*16384 + 4096 + t*16);
    gll16(Bp0 + ko, Lb + buf*16384 + 8192 + t*16);
    gll16(Bp1 + ko, Lb + buf*16384 + 12288 + t*16);
  };

  int offA[4], offB[4];
  #pragma unroll
  for (int m=0;m<4;m++) offA[m] = swz_off(wr*64 + m*16 + frow, kq);
  #pragma unroll
  for (int c=0;c<4;c++) offB[c] = swz_off(wc*64 + 4*frow + c, kq);

  f32x4 acc[4][4] = {};

  auto body = [&](int buf, int s){
    bf16x8 a4[4], b4[4];
    #pragma unroll
    for (int m=0;m<4;m++) a4[m] = *(const bf16x8*)(Lb + buf*16384 + offA[m]);
    #pragma unroll
    for (int c=0;c<4;c++) b4[c] = *(const bf16x8*)(Lb + buf*16384 + 8192 + offB[c]);
    const bool doStage = (s + 2 < NTQ);
    if (doStage){ int nb = buf+2; if (nb>=3) nb-=3; stage(nb, s+2); }
    asm volatile("s_waitcnt lgkmcnt(0)" ::: "memory");
    __builtin_amdgcn_sched_barrier(0);
    __builtin_amdgcn_s_setprio(1);
    #pragma unroll
    for (int m=0;m<4;m++)
      #pragma unroll
      for (int c=0;c<4;c++)
        acc[m][c] = MFMA_(a4[m], b4[c], acc[m][c]);
    __builtin_amdgcn_s_setprio(0);
    __builtin_amdgcn_sched_barrier(0);
    if (s + 1 < NTQ){
      if (doStage) asm volatile("s_waitcnt vmcnt(4)" ::: "memory");
      else         asm volatile("s_waitcnt vmcnt(0)" ::: "memory");
      __builtin_amdgcn_s_barrier();
    }
  };

  stage(0, 0); stage(1, 1);
  asm volatile("s_waitcnt vmcnt(4)" ::: "memory");
  __builtin_amdgcn_s_barrier();

  #pragma unroll
  for (int i = 0; i < 5; i++){
    body(0, i*3);
    body(1, i*3+1);
    body(2, i*3+2);
  }
  body(0, 15);

  const int c = bcol + wc*64 + 4*frow;
  const float4 bi = *(const float4*)(bias + c);
  #pragma unroll
  for (int m=0;m<4;m++){
    #pragma unroll
    for (int r=0;r<4;r++){
      const int rr = brow + wr*64 + m*16 + kq*4 + r;
      const float4 rv = *(const float4*)(res + (size_t)rr*NC + c);
      float4 ov;
      ov.x = acc[m][0][r] + bi.x + rv.x;
      ov.y = acc[m][1][r] + bi.y + rv.y;
      ov.z = acc[m][2][r] + bi.z + rv.z;
      ov.w = acc[m][3][r] + bi.w + rv.w;
      *(float4*)&out[(size_t)rr*NC + c] = ov;
    }
  }
}

extern "C" void kernel_launch(void* const* d_in, const int* in_sizes, int n_in,
                              void* d_out, int out_size, void* d_ws, size_t ws_size,
                              hipStream_t stream){
  const float* x   = (const float*)d_in[0];
  const float* gsc = (const float*)d_in[1];
  const float* gbi = (const float*)d_in[2];
  const float* wq  = (const float*)d_in[3];
  const float* bq  = (const float*)d_in[4];
  const float* wk  = (const float*)d_in[5];
  const float* bk  = (const float*)d_in[6];
  const float* wv  = (const float*)d_in[7];
  const float* bv  = (const float*)d_in[8];
  const float* wo  = (const float*)d_in[9];
  const float* bo  = (const float*)d_in[10];
  float* out = (float*)d_out;

  char* wsp = (char*)d_ws;
  size_t off = 0;
  auto alloc = [&](size_t bytes)->void*{ void* p = wsp + off; off += (bytes + 255) & ~(size_t)255; return p; };
  float* stats   = (float*)alloc((size_t)NB*NG*2*sizeof(float));
  float* sums    = (float*)alloc((size_t)NM*sizeof(float));
  float* partsum = (float*)alloc((size_t)NM*64*sizeof(float));
  u16* xbf   = (u16*)alloc((size_t)NM*NC*2);   // dead after gn_apply2
  u16* hn    = (u16*)alloc((size_t)NM*NC*2);   // dead after k_qkv
  u16* wqkvT = (u16*)alloc((size_t)3*NC*NC*2);
  u16* woT   = (u16*)alloc((size_t)NC*NC*2);
  uint8_t* q8 = (uint8_t*)alloc((size_t)NM*NC);
  uint8_t* k8 = (uint8_t*)alloc((size_t)NM*NC);
  uint8_t* v8 = (uint8_t*)alloc((size_t)NM*NC);   // [b][c][seq] fp8
  u16* o     = (u16*)alloc((size_t)NM*NC*2);
  uint8_t* P8 = (uint8_t*)alloc((size_t)NB*NSEQ*NSEQ);
  u16* opart = xbf;  // PV split-K partials [2][NM][NC] alias xbf+hn (32 MiB, both dead)

  k_zero<<<1,256,0,stream>>>(stats, NB*NG*2);
  k_gn_stats2<<<NB*64,256,0,stream>>>(x, xbf, stats);
  k_gn_apply2<<<4096,256,0,stream>>>(xbf, stats, gsc, gbi, hn);
  k_wtrans4<<<4096,256,0,stream>>>(wq, wk, wv, wo, wqkvT, woT);

  // QKV projection: q,k,v all fp8 out
  k_qkv<<<dim3(6,128,1),512,0,stream>>>(hn, wqkvT, q8, k8, v8, bq, bk, bv);

  const float scale = 0.044194173824159216f;  // 512^-0.5
  // QK^T fp8 -> fp8 P + row partials
  k_qk8<<<dim3(16,32,NB),512,0,stream>>>(q8, k8, P8, partsum, scale);
  k_sumred<<<NM/4,256,0,stream>>>(partsum, sums);
  // PV fp8 split-K=2 (qk8-clone structure, 2 blocks/CU)
  k_pv8<<<dim3(2,32,8),512,0,stream>>>(P8, v8, opart);
  k_pvred<<<NM*NC/8/256,256,0,stream>>>(opart, sums, o);
  // output projection + bias + residual
  k_t256o<<<dim3(4,128,1),256,0,stream>>>(o, woT, out, bo, x);
}